// Round 10
// baseline (669.310 us; speedup 1.0000x reference)
//
#include <hip/hip_runtime.h>

#define BN_EPS 1e-4f
#define BKT_SH 7          // 128 outputs per bucket
#define NBUCK_MAX 2560
#define CBLK 256          // blocks in count/place phases
#define LDSCAP 15872      // max records per place-block
#define P3CAP 2048        // max records per bucket

typedef __attribute__((ext_vector_type(8))) short short8;   // 8 bf16
typedef __attribute__((ext_vector_type(4))) float f32x4;    // MFMA acc
typedef __attribute__((ext_vector_type(4))) float floatv4;
typedef unsigned int uint;

union U4S8 { uint4 u; short8 s; };

// float -> bf16 bits, round-to-nearest-even
static __device__ __forceinline__ unsigned short f2bf(float f) {
    unsigned u = __float_as_uint(f);
    unsigned r = (u + 0x7FFFu + ((u >> 16) & 1u)) >> 16;
    return (unsigned short)r;
}

// ---------------- BN stats over f32 [N,32]: per-channel sum & sumsq -------
__global__ void stats_f32(const float* __restrict__ x,
                          float* __restrict__ stats, int total4) {
    const int t = threadIdx.x;
    long idx = (long)blockIdx.x * 256 + t;
    const long stride = (long)gridDim.x * 256;
    float s[4] = {0.f, 0.f, 0.f, 0.f}, q[4] = {0.f, 0.f, 0.f, 0.f};
    const floatv4* x4 = (const floatv4*)x;
    for (long e = idx; e < total4; e += stride) {
        floatv4 v = x4[e];
#pragma unroll
        for (int j = 0; j < 4; ++j) { s[j] += v[j]; q[j] += v[j] * v[j]; }
    }
    __shared__ float red[256][4];
#pragma unroll
    for (int j = 0; j < 4; ++j) red[t][j] = s[j];
    __syncthreads();
    if (t < 32) {
        float a = 0.f;
        const int grp = t >> 2, j = t & 3;
#pragma unroll
        for (int m = 0; m < 32; ++m) a += red[grp + 8 * m][j];
        atomicAdd(&stats[t], a);
    }
    __syncthreads();
#pragma unroll
    for (int j = 0; j < 4; ++j) red[t][j] = q[j];
    __syncthreads();
    if (t < 32) {
        float a = 0.f;
        const int grp = t >> 2, j = t & 3;
#pragma unroll
        for (int m = 0; m < 32; ++m) a += red[grp + 8 * m][j];
        atomicAdd(&stats[32 + t], a);
    }
}

// ---------------- BN stats over bf16 [N,32] ----------------
__global__ void stats_bf16(const ushort* __restrict__ x,
                           float* __restrict__ stats, int n8) {
    const int t = threadIdx.x;
    long idx = (long)blockIdx.x * 256 + t;
    const long stride = (long)gridDim.x * 256;
    float s[8] = {0}, q[8] = {0};
    const uint4* x8 = (const uint4*)x;
    for (long e = idx; e < n8; e += stride) {
        uint4 v = x8[e];
        uint w0 = v.x, w1 = v.y, w2 = v.z, w3 = v.w;
        float f0 = __uint_as_float(w0 << 16), f1 = __uint_as_float(w0 & 0xFFFF0000u);
        float f2 = __uint_as_float(w1 << 16), f3 = __uint_as_float(w1 & 0xFFFF0000u);
        float f4 = __uint_as_float(w2 << 16), f5 = __uint_as_float(w2 & 0xFFFF0000u);
        float f6 = __uint_as_float(w3 << 16), f7 = __uint_as_float(w3 & 0xFFFF0000u);
        s[0]+=f0; q[0]+=f0*f0; s[1]+=f1; q[1]+=f1*f1;
        s[2]+=f2; q[2]+=f2*f2; s[3]+=f3; q[3]+=f3*f3;
        s[4]+=f4; q[4]+=f4*f4; s[5]+=f5; q[5]+=f5*f5;
        s[6]+=f6; q[6]+=f6*f6; s[7]+=f7; q[7]+=f7*f7;
    }
    __shared__ float red[256][8];
#pragma unroll
    for (int j = 0; j < 8; ++j) red[t][j] = s[j];
    __syncthreads();
    if (t < 32) {
        float a = 0.f;
        const int grp = t >> 3, j = t & 7;
#pragma unroll
        for (int m = 0; m < 64; ++m) a += red[grp + 4 * m][j];
        atomicAdd(&stats[t], a);
    }
    __syncthreads();
#pragma unroll
    for (int j = 0; j < 8; ++j) red[t][j] = q[j];
    __syncthreads();
    if (t < 32) {
        float a = 0.f;
        const int grp = t >> 3, j = t & 7;
#pragma unroll
        for (int m = 0; m < 64; ++m) a += red[grp + 4 * m][j];
        atomicAdd(&stats[32 + t], a);
    }
}

// ---------------- bn_relu + cast to bf16 (f32 input) ----------------
__global__ void bnrelu_f32(const float* __restrict__ x,
                           const float* __restrict__ stats,
                           ushort* __restrict__ xb, int n8, int N) {
    int idx = blockIdx.x * 256 + threadIdx.x;
    if (idx >= n8) return;
    const int c0 = (idx & 3) * 8;
    const float invN = 1.0f / (float)N;
    floatv4 v0 = *(const floatv4*)(x + (size_t)idx * 8);
    floatv4 v1 = *(const floatv4*)(x + (size_t)idx * 8 + 4);
    uint r[8];
#pragma unroll
    for (int j = 0; j < 8; ++j) {
        const int c = c0 + j;
        float mu = stats[c] * invN;
        float var = stats[32 + c] * invN - mu * mu;
        float rs = rsqrtf(var + BN_EPS);
        float f = (j < 4) ? v0[j] : v1[j - 4];
        float xn = fmaxf((f - mu) * rs, 0.f);
        r[j] = (uint)f2bf(xn);
    }
    uint4 o;
    o.x = r[0] | (r[1] << 16); o.y = r[2] | (r[3] << 16);
    o.z = r[4] | (r[5] << 16); o.w = r[6] | (r[7] << 16);
    *(uint4*)(xb + (size_t)idx * 8) = o;
}

// ---------------- bn_relu + cast to bf16 (bf16 input) ----------------
__global__ void bnrelu_bf16(const ushort* __restrict__ h,
                            const float* __restrict__ stats,
                            ushort* __restrict__ xb, int n8, int N) {
    int idx = blockIdx.x * 256 + threadIdx.x;
    if (idx >= n8) return;
    const int c0 = (idx & 3) * 8;
    const float invN = 1.0f / (float)N;
    uint4 v = *(const uint4*)(h + (size_t)idx * 8);
    uint w[4] = {v.x, v.y, v.z, v.w};
    uint r[8];
#pragma unroll
    for (int j = 0; j < 8; ++j) {
        const int c = c0 + j;
        float mu = stats[c] * invN;
        float var = stats[32 + c] * invN - mu * mu;
        float rs = rsqrtf(var + BN_EPS);
        uint bits = (j & 1) ? (w[j >> 1] & 0xFFFF0000u) : (w[j >> 1] << 16);
        float f = __uint_as_float(bits);
        float xn = fmaxf((f - mu) * rs, 0.f);
        r[j] = (uint)f2bf(xn);
    }
    uint4 o;
    o.x = r[0] | (r[1] << 16); o.y = r[2] | (r[3] << 16);
    o.z = r[4] | (r[5] << 16); o.w = r[6] | (r[7] << 16);
    *(uint4*)(xb + (size_t)idx * 8) = o;
}

// ---------------- zero row N of xb (safe gather target) ----------------
__global__ void zrow(ushort* __restrict__ xb, int N) {
    if (threadIdx.x < 32) xb[(size_t)N * 32 + threadIdx.x] = 0;
}

// ---------------- W [27][cin][cout] f32 -> Wt [27][cout][cin] bf16 --------
__global__ void wcvt(const float* __restrict__ W, ushort* __restrict__ Wt) {
    int idx = blockIdx.x * 256 + threadIdx.x;
    if (idx >= 27 * 1024) return;
    int k = idx >> 10, r = idx & 1023, co = r >> 5, ci = r & 31;
    Wt[(k << 10) + (co << 5) + ci] = f2bf(W[(k << 10) + (ci << 5) + co]);
}

// ============ CSR build: atomic-free MSD bucket sort (round-6 exact) ======

__global__ void p1_count(const int* __restrict__ pin, const int* __restrict__ pout,
                         uint* __restrict__ cntmat, int KP, int chunk, int nbuck) {
    __shared__ uint H[NBUCK_MAX];
    const int t = threadIdx.x;
    for (int i = t; i < nbuck; i += 256) H[i] = 0;
    __syncthreads();
    const int r0 = blockIdx.x * chunk;
    const int r1 = min(KP, r0 + chunk);
    for (int r = r0 + t; r < r1; r += 256)
        if (pin[r] >= 0) atomicAdd(&H[((uint)pout[r]) >> BKT_SH], 1u);
    __syncthreads();
    uint* row = cntmat + (size_t)blockIdx.x * nbuck;
    for (int i = t; i < nbuck; i += 256) row[i] = H[i];
}

__global__ void p2_colscan(uint* __restrict__ cntmat, uint* __restrict__ btot,
                           int nbuck) {
    const int b = blockIdx.x;
    const int t = threadIdx.x;
    __shared__ uint sh[CBLK];
    uint v = cntmat[(size_t)t * nbuck + b];
    sh[t] = v;
    __syncthreads();
    for (int off = 1; off < CBLK; off <<= 1) {
        uint y = (t >= off) ? sh[t - off] : 0;
        __syncthreads();
        sh[t] += y;
        __syncthreads();
    }
    cntmat[(size_t)t * nbuck + b] = sh[t] - v;   // exclusive over blocks
    if (t == CBLK - 1) btot[b] = sh[CBLK - 1];
}

__global__ void p3_bucketscan(const uint* __restrict__ btot, uint* __restrict__ bbase,
                              uint* __restrict__ starts, int nbuck, int N) {
    const int t = threadIdx.x;
    __shared__ uint part[256];
    uint loc[10]; uint s = 0;
#pragma unroll
    for (int u = 0; u < 10; ++u) {
        int i = t * 10 + u;
        loc[u] = (i < nbuck) ? btot[i] : 0;
        s += loc[u];
    }
    part[t] = s;
    __syncthreads();
    for (int off = 1; off < 256; off <<= 1) {
        uint y = (t >= off) ? part[t - off] : 0;
        __syncthreads();
        part[t] += y;
        __syncthreads();
    }
    uint run = part[t] - s;
#pragma unroll
    for (int u = 0; u < 10; ++u) {
        int i = t * 10 + u;
        if (i < nbuck) { bbase[i] = run; run += loc[u]; }
    }
    if (t == 255) { bbase[nbuck] = run; starts[N] = run; }
}

__global__ __launch_bounds__(256, 1)
void p4_place(const int* __restrict__ pin, const int* __restrict__ pout,
              const uint* __restrict__ cntmat, const uint* __restrict__ bbase,
              uint* __restrict__ tmp, int KP, int P, int chunk, int nbuck) {
    __shared__ uint recs[LDSCAP];
    __shared__ uint H[NBUCK_MAX + 1];
    __shared__ uint C[NBUCK_MAX];
    __shared__ uint part[256];
    const int t = threadIdx.x;
    const int j = blockIdx.x;
    for (int i = t; i < nbuck; i += 256) H[i] = 0;
    __syncthreads();
    const int r0 = j * chunk;
    const int r1 = min(KP, r0 + chunk);
    for (int r = r0 + t; r < r1; r += 256)
        if (pin[r] >= 0) atomicAdd(&H[((uint)pout[r]) >> BKT_SH], 1u);
    __syncthreads();
    uint loc[10]; uint s = 0;
#pragma unroll
    for (int u = 0; u < 10; ++u) {
        int i = t * 10 + u;
        loc[u] = (i < nbuck) ? H[i] : 0;
        s += loc[u];
    }
    __syncthreads();
    part[t] = s;
    __syncthreads();
    for (int off = 1; off < 256; off <<= 1) {
        uint y = (t >= off) ? part[t - off] : 0;
        __syncthreads();
        part[t] += y;
        __syncthreads();
    }
    uint run = part[t] - s;
#pragma unroll
    for (int u = 0; u < 10; ++u) {
        int i = t * 10 + u;
        if (i < nbuck) { uint c = loc[u]; H[i] = run; run += c; }
    }
    if (t == 255) H[nbuck] = run;
    __syncthreads();
    for (int i = t; i < nbuck; i += 256) C[i] = H[i];   // cursors
    __syncthreads();
    for (int r = r0 + t; r < r1; r += 256) {
        int ii = pin[r];
        if (ii < 0) continue;
        uint po = (uint)pout[r];
        uint b = po >> BKT_SH;
        uint k = (uint)r / (uint)P;
        uint pos = atomicAdd(&C[b], 1u);
        recs[pos] = ((po & 127u) << 24) | (k << 19) | (uint)ii;
    }
    __syncthreads();
    const uint tot = H[nbuck];
    for (int i = t; i < nbuck; i += 256)
        C[i] = bbase[i] + cntmat[(size_t)j * nbuck + i] - H[i];  // dest bias
    __syncthreads();
    for (uint sdx = t; sdx < tot; sdx += 256) {
        uint lo = 0, hi = (uint)nbuck;
        while (hi - lo > 1) { uint mid = (lo + hi) >> 1; if (H[mid] <= sdx) lo = mid; else hi = mid; }
        tmp[C[lo] + sdx] = recs[sdx];
    }
}

__global__ void p5_fine(const uint* __restrict__ tmp, const uint* __restrict__ bbase,
                        uint* __restrict__ entries, uint* __restrict__ starts, int N) {
    __shared__ uint recs[P3CAP];
    __shared__ uint cnt[128];
    __shared__ uint curl[128];
    const int b = blockIdx.x;
    const int t = threadIdx.x;
    const uint e0 = bbase[b];
    uint nrec = bbase[b + 1] - e0;
    if (nrec > P3CAP) nrec = P3CAP;
    for (uint s = t; s < nrec; s += 256) recs[s] = tmp[e0 + s];
    if (t < 128) { cnt[t] = 0; curl[t] = 0; }
    __syncthreads();
    for (uint s = t; s < nrec; s += 256) atomicAdd(&cnt[recs[s] >> 24], 1u);
    __syncthreads();
    uint orig = (t < 128) ? cnt[t] : 0;
    for (int off = 1; off < 128; off <<= 1) {
        uint y = (t < 128 && t >= off) ? cnt[t - off] : 0;
        __syncthreads();
        if (t < 128) cnt[t] += y;
        __syncthreads();
    }
    if (t < 128) cnt[t] -= orig;
    __syncthreads();
    const int o0 = b << BKT_SH;
    if (t < 128 && o0 + t < N) starts[o0 + t] = e0 + cnt[t];
    for (uint s = t; s < nrec; s += 256) {
        uint lo = recs[s] >> 24;
        uint idx = atomicAdd(&curl[lo], 1u);
        entries[e0 + cnt[lo] + idx] = recs[s] & 0x00FFFFFFu;
    }
}

// ------- CSR-gather MFMA conv: rank-based walk, ZERO divergence at MFMA ----
// entry = (k<<19)|pin. In-conv sort groups each output's list by k. Per k:
// (1) per-lane count scan (no MFMA inside -- divergence harmless)
// (2) wave-max via shfl_xor, readfirstlane -> SGPR-uniform loop bound
// (3) branch-free MFMA loop: cndmask-selected address, full-exec MFMA.
template <bool FINAL>
__global__ void conv_csr(const ushort* __restrict__ xb,   // [N+1][32], row N = 0
                         const ushort* __restrict__ Wt,   // [27][32 cout][32 cin]
                         const uint* __restrict__ starts,
                         const uint* __restrict__ entries,
                         const float* __restrict__ iden,
                         float* __restrict__ outf,
                         ushort* __restrict__ outb,
                         int N) {
    const int w  = threadIdx.x >> 6;
    const int l  = threadIdx.x & 63;
    const int m  = l & 15;     // output-within-tile / C col (cout)
    const int iq = l >> 4;     // cin chunk iq*8..+7 ; C rows iq*4..+3
    const int o0 = (blockIdx.x * 4 + w) * 16;

    __shared__ uint eld[4][384];

    const bool tv = (o0 < N);
    uint s0 = 0, sm = 0, se = 0, total = 0;
    if (tv) {
        s0 = starts[o0];
        sm = starts[o0 + m];
        se = starts[o0 + m + 1];
        total = starts[o0 + 16] - s0;
        if (total > 384) total = 384;
        for (uint t = l; t < total; t += 64)
            eld[w][t] = entries[s0 + t];
    }
    __syncthreads();

    // per-lane insertion sort of its list (groups by k; u32 order)
    if (tv && iq == 0) {
        const uint a = sm - s0, bnd = se - s0;
        for (uint i = a + 1; i < bnd; ++i) {
            uint key = eld[w][i];
            uint j = i;
            while (j > a && eld[w][j - 1] > key) { eld[w][j] = eld[w][j - 1]; --j; }
            eld[w][j] = key;
        }
    }
    __syncthreads();

    f32x4 c0 = {0.f, 0.f, 0.f, 0.f};
    f32x4 c1 = {0.f, 0.f, 0.f, 0.f};

    uint q = sm - s0;
    const uint e = se - s0;

    for (int k = 0; k < 27; ++k) {
        const ushort* wk = Wt + (k << 10);
        U4S8 b0, b1;
        b0.u = *(const uint4*)(wk + m * 32 + iq * 8);
        b1.u = *(const uint4*)(wk + (m + 16) * 32 + iq * 8);

        // (1) count this lane's consecutive k-entries (MFMA-free loop)
        uint cnt = 0;
        while (q + cnt < e && (eld[w][q + cnt] >> 19) == (uint)k) ++cnt;

        // (2) wave-uniform round count
        uint rounds = cnt;
#pragma unroll
        for (int off = 32; off > 0; off >>= 1) {
            uint v = (uint)__shfl_xor((int)rounds, off);
            rounds = (rounds > v) ? rounds : v;
        }
        rounds = (uint)__builtin_amdgcn_readfirstlane((int)rounds);

        // (3) branch-free MFMA rounds
        for (uint r = 0; r < rounds; ++r) {
            uint idx = q + r;
            if (idx > 383u) idx = 383u;           // clamp (value unused if r>=cnt)
            uint ev = eld[w][idx];
            uint pi = (r < cnt) ? (ev & 0x7FFFFu) : (uint)N;   // zero row if idle
            U4S8 a;
            a.u = *(const uint4*)(xb + (size_t)pi * 32 + iq * 8);
            c0 = __builtin_amdgcn_mfma_f32_16x16x32_bf16(a.s, b0.s, c0, 0, 0, 0);
            c1 = __builtin_amdgcn_mfma_f32_16x16x32_bf16(a.s, b1.s, c1, 0, 0, 0);
        }
        q += cnt;
    }

    if (tv) {
#pragma unroll
        for (int j = 0; j < 4; ++j) {
            const long ro = (long)(o0 + iq * 4 + j) * 32;
            if (FINAL) {
                outf[ro + m]      = c0[j] + iden[ro + m];
                outf[ro + 16 + m] = c1[j] + iden[ro + 16 + m];
            } else {
                outb[ro + m]      = f2bf(c0[j]);
                outb[ro + 16 + m] = f2bf(c1[j]);
            }
        }
    }
}

// ---------------- downsample scatter-mean ----------------
__global__ void ds_scatter(const float* __restrict__ xyz,
                           const int* __restrict__ batch,
                           const int* __restrict__ din,
                           const int* __restrict__ dout,
                           float* __restrict__ dsum, float* __restrict__ dcnt,
                           int P2n) {
    int p = blockIdx.x * 256 + threadIdx.x;
    if (p >= P2n) return;
    int i = din[p];
    if (i < 0) return;
    int o = dout[p];
    atomicAdd(&dsum[o * 4 + 0], xyz[(long)i * 3 + 0]);
    atomicAdd(&dsum[o * 4 + 1], xyz[(long)i * 3 + 1]);
    atomicAdd(&dsum[o * 4 + 2], xyz[(long)i * 3 + 2]);
    atomicAdd(&dsum[o * 4 + 3], (float)batch[i]);
    atomicAdd(&dcnt[o], 1.0f);
}

__global__ void ds_finalize(const float* __restrict__ dsum,
                            const float* __restrict__ dcnt,
                            float* __restrict__ out_xyz,
                            float* __restrict__ out_batch, int M) {
    int o = blockIdx.x * 256 + threadIdx.x;
    if (o >= M) return;
    float c = fmaxf(dcnt[o], 1.0f);
    float inv = 1.0f / c;
    out_xyz[(long)o * 3 + 0] = dsum[o * 4 + 0] * inv;
    out_xyz[(long)o * 3 + 1] = dsum[o * 4 + 1] * inv;
    out_xyz[(long)o * 3 + 2] = dsum[o * 4 + 2] * inv;
    out_batch[o] = dsum[o * 4 + 3] * inv;
}

extern "C" void kernel_launch(void* const* d_in, const int* in_sizes, int n_in,
                              void* d_out, int out_size, void* d_ws, size_t ws_size,
                              hipStream_t stream) {
    const float* feats = (const float*)d_in[0];
    const float* xyz   = (const float*)d_in[1];
    const int*   batch = (const int*)d_in[2];
    const int*   pin   = (const int*)d_in[3];
    const int*   pout  = (const int*)d_in[4];
    const int*   dsin  = (const int*)d_in[5];
    const int*   dsout = (const int*)d_in[6];
    const float* W1    = (const float*)d_in[7];
    const float* W2    = (const float*)d_in[8];

    const int N   = in_sizes[0] / 32;
    const int K   = 27;
    const int P   = in_sizes[3] / K;
    const int KP  = K * P;
    const int P2n = in_sizes[5];
    const int M   = (out_size - N * 32) / 4;
    const int nbuck = (N + 127) >> BKT_SH;       // 2344 for N=300000
    const int chunk = (KP + CBLK - 1) / CBLK;    // 15821 <= LDSCAP

    auto align256 = [](size_t x) { return (x + 255) & ~(size_t)255; };
    char* base = (char*)d_ws;
    size_t off = 0;
    float* stats1 = (float*)(base + off); off += 256;
    float* stats2 = (float*)(base + off); off += 256;
    float* dsum   = (float*)(base + off); off += (size_t)M * 16;
    float* dcnt   = (float*)(base + off); off = align256(off + (size_t)M * 4);
    const size_t zero_end = off;
    uint* cntmat  = (uint*)(base + off);  off = align256(off + (size_t)CBLK * nbuck * 4);
    uint* btot    = (uint*)(base + off);  off = align256(off + (size_t)nbuck * 4);
    uint* bbase   = (uint*)(base + off);  off = align256(off + (size_t)(nbuck + 1) * 4);
    uint* starts  = (uint*)(base + off);  off = align256(off + (size_t)(N + 1) * 4);
    uint* tmp     = (uint*)(base + off);  off = align256(off + (size_t)KP * 4);
    uint* entries = (uint*)(base + off);  off = align256(off + (size_t)KP * 4);
    ushort* Wt1   = (ushort*)(base + off); off = align256(off + 27 * 1024 * 2);
    ushort* Wt2   = (ushort*)(base + off); off = align256(off + 27 * 1024 * 2);
    ushort* xb    = (ushort*)(base + off); off = align256(off + (size_t)(N + 1) * 64);
    ushort* hacc  = (ushort*)(base + off); off = align256(off + (size_t)N * 64);

    hipMemsetAsync(d_ws, 0, zero_end, stream);

    // W -> bf16 transposed; zero gather-target row N of xb
    wcvt<<<108, 256, 0, stream>>>(W1, Wt1);
    wcvt<<<108, 256, 0, stream>>>(W2, Wt2);
    zrow<<<1, 64, 0, stream>>>(xb, N);

    // CSR build (atomic-free; shared by both convs)
    p1_count<<<CBLK, 256, 0, stream>>>(pin, pout, cntmat, KP, chunk, nbuck);
    p2_colscan<<<nbuck, CBLK, 0, stream>>>(cntmat, btot, nbuck);
    p3_bucketscan<<<1, 256, 0, stream>>>(btot, bbase, starts, nbuck, N);
    p4_place<<<CBLK, 256, 0, stream>>>(pin, pout, cntmat, bbase, tmp, KP, P, chunk, nbuck);
    p5_fine<<<nbuck, 256, 0, stream>>>(tmp, bbase, entries, starts, N);

    // conv1: bn_relu(feats) -> W1 -> hacc (bf16)
    stats_f32<<<1024, 256, 0, stream>>>(feats, stats1, N * 8);
    bnrelu_f32<<<(N * 4 + 255) / 256, 256, 0, stream>>>(feats, stats1, xb, N * 4, N);
    const int cblocks = (N / 16 + 3) / 4;
    conv_csr<false><<<cblocks, 256, 0, stream>>>(xb, Wt1, starts, entries,
                                                 nullptr, nullptr, hacc, N);

    // conv2: bn_relu(hacc) -> W2 -> out (+ identity feats)
    stats_bf16<<<1024, 256, 0, stream>>>(hacc, stats2, N * 4);
    bnrelu_bf16<<<(N * 4 + 255) / 256, 256, 0, stream>>>(hacc, stats2, xb, N * 4, N);
    float* out = (float*)d_out;
    conv_csr<true><<<cblocks, 256, 0, stream>>>(xb, Wt2, starts, entries,
                                                feats, out, nullptr, N);

    // downsample scatter-mean
    ds_scatter<<<(P2n + 255) / 256, 256, 0, stream>>>(xyz, batch, dsin, dsout,
                                                      dsum, dcnt, P2n);
    ds_finalize<<<(M + 255) / 256, 256, 0, stream>>>(dsum, dcnt,
                                                     out + (size_t)N * 32,
                                                     out + (size_t)N * 32 + (size_t)3 * M,
                                                     M);
}

// Round 11
// 617.068 us; speedup vs baseline: 1.0847x; 1.0847x over previous
//
#include <hip/hip_runtime.h>

#define BN_EPS 1e-4f
#define BKT_SH 7          // 128 outputs per bucket
#define NBUCK_MAX 2560
#define CBLK 256          // blocks in count/place phases
#define LDSCAP 15872      // max records per place-block
#define P3CAP 2048        // max records per bucket

typedef __attribute__((ext_vector_type(8))) short short8;   // 8 bf16
typedef __attribute__((ext_vector_type(4))) float f32x4;    // MFMA acc
typedef __attribute__((ext_vector_type(4))) float floatv4;
typedef unsigned int uint;

union U4S8 { uint4 u; short8 s; };

// float -> bf16 bits, round-to-nearest-even
static __device__ __forceinline__ unsigned short f2bf(float f) {
    unsigned u = __float_as_uint(f);
    unsigned r = (u + 0x7FFFu + ((u >> 16) & 1u)) >> 16;
    return (unsigned short)r;
}

// ---------------- BN stats over f32 [N,32]: per-channel sum & sumsq -------
__global__ void stats_f32(const float* __restrict__ x,
                          float* __restrict__ stats, int total4) {
    const int t = threadIdx.x;
    long idx = (long)blockIdx.x * 256 + t;
    const long stride = (long)gridDim.x * 256;
    float s[4] = {0.f, 0.f, 0.f, 0.f}, q[4] = {0.f, 0.f, 0.f, 0.f};
    const floatv4* x4 = (const floatv4*)x;
    for (long e = idx; e < total4; e += stride) {
        floatv4 v = x4[e];
#pragma unroll
        for (int j = 0; j < 4; ++j) { s[j] += v[j]; q[j] += v[j] * v[j]; }
    }
    __shared__ float red[256][4];
#pragma unroll
    for (int j = 0; j < 4; ++j) red[t][j] = s[j];
    __syncthreads();
    if (t < 32) {
        float a = 0.f;
        const int grp = t >> 2, j = t & 3;
#pragma unroll
        for (int m = 0; m < 32; ++m) a += red[grp + 8 * m][j];
        atomicAdd(&stats[t], a);
    }
    __syncthreads();
#pragma unroll
    for (int j = 0; j < 4; ++j) red[t][j] = q[j];
    __syncthreads();
    if (t < 32) {
        float a = 0.f;
        const int grp = t >> 2, j = t & 3;
#pragma unroll
        for (int m = 0; m < 32; ++m) a += red[grp + 8 * m][j];
        atomicAdd(&stats[32 + t], a);
    }
}

// ---------------- BN stats over bf16 [N,32] ----------------
__global__ void stats_bf16(const ushort* __restrict__ x,
                           float* __restrict__ stats, int n8) {
    const int t = threadIdx.x;
    long idx = (long)blockIdx.x * 256 + t;
    const long stride = (long)gridDim.x * 256;
    float s[8] = {0}, q[8] = {0};
    const uint4* x8 = (const uint4*)x;
    for (long e = idx; e < n8; e += stride) {
        uint4 v = x8[e];
        uint w0 = v.x, w1 = v.y, w2 = v.z, w3 = v.w;
        float f0 = __uint_as_float(w0 << 16), f1 = __uint_as_float(w0 & 0xFFFF0000u);
        float f2 = __uint_as_float(w1 << 16), f3 = __uint_as_float(w1 & 0xFFFF0000u);
        float f4 = __uint_as_float(w2 << 16), f5 = __uint_as_float(w2 & 0xFFFF0000u);
        float f6 = __uint_as_float(w3 << 16), f7 = __uint_as_float(w3 & 0xFFFF0000u);
        s[0]+=f0; q[0]+=f0*f0; s[1]+=f1; q[1]+=f1*f1;
        s[2]+=f2; q[2]+=f2*f2; s[3]+=f3; q[3]+=f3*f3;
        s[4]+=f4; q[4]+=f4*f4; s[5]+=f5; q[5]+=f5*f5;
        s[6]+=f6; q[6]+=f6*f6; s[7]+=f7; q[7]+=f7*f7;
    }
    __shared__ float red[256][8];
#pragma unroll
    for (int j = 0; j < 8; ++j) red[t][j] = s[j];
    __syncthreads();
    if (t < 32) {
        float a = 0.f;
        const int grp = t >> 3, j = t & 7;
#pragma unroll
        for (int m = 0; m < 64; ++m) a += red[grp + 4 * m][j];
        atomicAdd(&stats[t], a);
    }
    __syncthreads();
#pragma unroll
    for (int j = 0; j < 8; ++j) red[t][j] = q[j];
    __syncthreads();
    if (t < 32) {
        float a = 0.f;
        const int grp = t >> 3, j = t & 7;
#pragma unroll
        for (int m = 0; m < 64; ++m) a += red[grp + 4 * m][j];
        atomicAdd(&stats[32 + t], a);
    }
}

// ---------------- bn_relu + cast to bf16 (f32 input) ----------------
__global__ void bnrelu_f32(const float* __restrict__ x,
                           const float* __restrict__ stats,
                           ushort* __restrict__ xb, int n8, int N) {
    int idx = blockIdx.x * 256 + threadIdx.x;
    if (idx >= n8) return;
    const int c0 = (idx & 3) * 8;
    const float invN = 1.0f / (float)N;
    floatv4 v0 = *(const floatv4*)(x + (size_t)idx * 8);
    floatv4 v1 = *(const floatv4*)(x + (size_t)idx * 8 + 4);
    uint r[8];
#pragma unroll
    for (int j = 0; j < 8; ++j) {
        const int c = c0 + j;
        float mu = stats[c] * invN;
        float var = stats[32 + c] * invN - mu * mu;
        float rs = rsqrtf(var + BN_EPS);
        float f = (j < 4) ? v0[j] : v1[j - 4];
        float xn = fmaxf((f - mu) * rs, 0.f);
        r[j] = (uint)f2bf(xn);
    }
    uint4 o;
    o.x = r[0] | (r[1] << 16); o.y = r[2] | (r[3] << 16);
    o.z = r[4] | (r[5] << 16); o.w = r[6] | (r[7] << 16);
    *(uint4*)(xb + (size_t)idx * 8) = o;
}

// ---------------- bn_relu + cast to bf16 (bf16 input) ----------------
__global__ void bnrelu_bf16(const ushort* __restrict__ h,
                            const float* __restrict__ stats,
                            ushort* __restrict__ xb, int n8, int N) {
    int idx = blockIdx.x * 256 + threadIdx.x;
    if (idx >= n8) return;
    const int c0 = (idx & 3) * 8;
    const float invN = 1.0f / (float)N;
    uint4 v = *(const uint4*)(h + (size_t)idx * 8);
    uint w[4] = {v.x, v.y, v.z, v.w};
    uint r[8];
#pragma unroll
    for (int j = 0; j < 8; ++j) {
        const int c = c0 + j;
        float mu = stats[c] * invN;
        float var = stats[32 + c] * invN - mu * mu;
        float rs = rsqrtf(var + BN_EPS);
        uint bits = (j & 1) ? (w[j >> 1] & 0xFFFF0000u) : (w[j >> 1] << 16);
        float f = __uint_as_float(bits);
        float xn = fmaxf((f - mu) * rs, 0.f);
        r[j] = (uint)f2bf(xn);
    }
    uint4 o;
    o.x = r[0] | (r[1] << 16); o.y = r[2] | (r[3] << 16);
    o.z = r[4] | (r[5] << 16); o.w = r[6] | (r[7] << 16);
    *(uint4*)(xb + (size_t)idx * 8) = o;
}

// ------- prep: W1,W2 -> bf16 transposed; zero row N of xb (merged) --------
__global__ void prep(const float* __restrict__ W1, const float* __restrict__ W2,
                     ushort* __restrict__ Wt1, ushort* __restrict__ Wt2,
                     ushort* __restrict__ xb, int N) {
    int idx = blockIdx.x * 256 + threadIdx.x;
    if (idx < 27 * 1024) {
        int k = idx >> 10, r = idx & 1023, co = r >> 5, ci = r & 31;
        Wt1[(k << 10) + (co << 5) + ci] = f2bf(W1[(k << 10) + (ci << 5) + co]);
    } else if (idx < 2 * 27 * 1024) {
        int i2 = idx - 27 * 1024;
        int k = i2 >> 10, r = i2 & 1023, co = r >> 5, ci = r & 31;
        Wt2[(k << 10) + (co << 5) + ci] = f2bf(W2[(k << 10) + (ci << 5) + co]);
    } else if (idx < 2 * 27 * 1024 + 32) {
        xb[(size_t)N * 32 + (idx - 2 * 27 * 1024)] = 0;
    }
}

// ============ CSR build: atomic-free MSD bucket sort ============
// bucket = pout >> 7 (128 outputs each). Record payload = (k<<19)|pin (24b).

__global__ void p1_count(const int* __restrict__ pin, const int* __restrict__ pout,
                         uint* __restrict__ cntmat, int KP, int chunk, int nbuck) {
    __shared__ uint H[NBUCK_MAX];
    const int t = threadIdx.x;
    for (int i = t; i < nbuck; i += 256) H[i] = 0;
    __syncthreads();
    const int r0 = blockIdx.x * chunk;
    const int r1 = min(KP, r0 + chunk);
    for (int r = r0 + t; r < r1; r += 256)
        if (pin[r] >= 0) atomicAdd(&H[((uint)pout[r]) >> BKT_SH], 1u);
    __syncthreads();
    uint* row = cntmat + (size_t)blockIdx.x * nbuck;
    for (int i = t; i < nbuck; i += 256) row[i] = H[i];
}

// p2: per-bucket exclusive scan over CBLK blocks -- COALESCED tiled version.
// 256 threads = 64 buckets x 4 row-segments of 64. All cntmat accesses are
// contiguous across the bucket dimension.
__global__ void p2_colscan(uint* __restrict__ cntmat, uint* __restrict__ btot,
                           int nbuck) {
    const int tid = threadIdx.x;
    const int bi  = tid & 63;
    const int seg = tid >> 6;            // 0..3, rows seg*64 .. seg*64+63
    const int b   = blockIdx.x * 64 + bi;
    const bool valid = (b < nbuck);
    uint s = 0;
    if (valid) {
        for (int u = 0; u < 64; ++u)
            s += cntmat[(size_t)(seg * 64 + u) * nbuck + b];
    }
    __shared__ uint ss[4][64];
    ss[seg][bi] = s;
    __syncthreads();
    uint pre = 0;
    for (int g = 0; g < seg; ++g) pre += ss[g][bi];
    if (valid && seg == 3) btot[b] = pre + s;
    if (valid) {
        uint run = pre;
        for (int u = 0; u < 64; ++u) {
            size_t idx = (size_t)(seg * 64 + u) * nbuck + b;
            uint v = cntmat[idx];
            cntmat[idx] = run;           // exclusive over blocks
            run += v;
        }
    }
}

__global__ void p3_bucketscan(const uint* __restrict__ btot, uint* __restrict__ bbase,
                              uint* __restrict__ starts, int nbuck, int N) {
    const int t = threadIdx.x;
    __shared__ uint part[256];
    uint loc[10]; uint s = 0;
#pragma unroll
    for (int u = 0; u < 10; ++u) {
        int i = t * 10 + u;
        loc[u] = (i < nbuck) ? btot[i] : 0;
        s += loc[u];
    }
    part[t] = s;
    __syncthreads();
    for (int off = 1; off < 256; off <<= 1) {
        uint y = (t >= off) ? part[t - off] : 0;
        __syncthreads();
        part[t] += y;
        __syncthreads();
    }
    uint run = part[t] - s;
#pragma unroll
    for (int u = 0; u < 10; ++u) {
        int i = t * 10 + u;
        if (i < nbuck) { bbase[i] = run; run += loc[u]; }
    }
    if (t == 255) { bbase[nbuck] = run; starts[N] = run; }
}

__global__ __launch_bounds__(256, 1)
void p4_place(const int* __restrict__ pin, const int* __restrict__ pout,
              const uint* __restrict__ cntmat, const uint* __restrict__ bbase,
              uint* __restrict__ tmp, int KP, int P, int chunk, int nbuck) {
    __shared__ uint recs[LDSCAP];
    __shared__ uint H[NBUCK_MAX + 1];
    __shared__ uint C[NBUCK_MAX];
    __shared__ uint part[256];
    const int t = threadIdx.x;
    const int j = blockIdx.x;
    for (int i = t; i < nbuck; i += 256) H[i] = 0;
    __syncthreads();
    const int r0 = j * chunk;
    const int r1 = min(KP, r0 + chunk);
    for (int r = r0 + t; r < r1; r += 256)
        if (pin[r] >= 0) atomicAdd(&H[((uint)pout[r]) >> BKT_SH], 1u);
    __syncthreads();
    uint loc[10]; uint s = 0;
#pragma unroll
    for (int u = 0; u < 10; ++u) {
        int i = t * 10 + u;
        loc[u] = (i < nbuck) ? H[i] : 0;
        s += loc[u];
    }
    __syncthreads();
    part[t] = s;
    __syncthreads();
    for (int off = 1; off < 256; off <<= 1) {
        uint y = (t >= off) ? part[t - off] : 0;
        __syncthreads();
        part[t] += y;
        __syncthreads();
    }
    uint run = part[t] - s;
#pragma unroll
    for (int u = 0; u < 10; ++u) {
        int i = t * 10 + u;
        if (i < nbuck) { uint c = loc[u]; H[i] = run; run += c; }
    }
    if (t == 255) H[nbuck] = run;
    __syncthreads();
    for (int i = t; i < nbuck; i += 256) C[i] = H[i];   // cursors
    __syncthreads();
    for (int r = r0 + t; r < r1; r += 256) {
        int ii = pin[r];
        if (ii < 0) continue;
        uint po = (uint)pout[r];
        uint b = po >> BKT_SH;
        uint k = (uint)r / (uint)P;
        uint pos = atomicAdd(&C[b], 1u);
        recs[pos] = ((po & 127u) << 24) | (k << 19) | (uint)ii;
    }
    __syncthreads();
    const uint tot = H[nbuck];
    for (int i = t; i < nbuck; i += 256)
        C[i] = bbase[i] + cntmat[(size_t)j * nbuck + i] - H[i];  // dest bias
    __syncthreads();
    for (uint sdx = t; sdx < tot; sdx += 256) {
        uint lo = 0, hi = (uint)nbuck;
        while (hi - lo > 1) { uint mid = (lo + hi) >> 1; if (H[mid] <= sdx) lo = mid; else hi = mid; }
        tmp[C[lo] + sdx] = recs[sdx];
    }
}

__global__ void p5_fine(const uint* __restrict__ tmp, const uint* __restrict__ bbase,
                        uint* __restrict__ entries, uint* __restrict__ starts, int N) {
    __shared__ uint recs[P3CAP];
    __shared__ uint cnt[128];
    __shared__ uint curl[128];
    const int b = blockIdx.x;
    const int t = threadIdx.x;
    const uint e0 = bbase[b];
    uint nrec = bbase[b + 1] - e0;
    if (nrec > P3CAP) nrec = P3CAP;
    for (uint s = t; s < nrec; s += 256) recs[s] = tmp[e0 + s];
    if (t < 128) { cnt[t] = 0; curl[t] = 0; }
    __syncthreads();
    for (uint s = t; s < nrec; s += 256) atomicAdd(&cnt[recs[s] >> 24], 1u);
    __syncthreads();
    uint orig = (t < 128) ? cnt[t] : 0;
    for (int off = 1; off < 128; off <<= 1) {
        uint y = (t < 128 && t >= off) ? cnt[t - off] : 0;
        __syncthreads();
        if (t < 128) cnt[t] += y;
        __syncthreads();
    }
    if (t < 128) cnt[t] -= orig;
    __syncthreads();
    const int o0 = b << BKT_SH;
    if (t < 128 && o0 + t < N) starts[o0 + t] = e0 + cnt[t];
    for (uint s = t; s < nrec; s += 256) {
        uint lo = recs[s] >> 24;
        uint idx = atomicAdd(&curl[lo], 1u);
        entries[e0 + cnt[lo] + idx] = recs[s] & 0x00FFFFFFu;
    }
}

// ------- CSR-gather MFMA conv: wave-independent (NO block barriers) -------
// Round-6 VALU walk. eld[w] is strictly per-wave; cross-wave __syncthreads
// replaced by wave-local lgkmcnt fences so the 4 waves run untethered.
template <bool FINAL>
__global__ void conv_csr(const ushort* __restrict__ xb,   // [N+1][32], row N = 0
                         const ushort* __restrict__ Wt,   // [27][32 cout][32 cin]
                         const uint* __restrict__ starts,
                         const uint* __restrict__ entries,
                         const float* __restrict__ iden,
                         float* __restrict__ outf,
                         ushort* __restrict__ outb,
                         int N) {
    const int w  = threadIdx.x >> 6;
    const int l  = threadIdx.x & 63;
    const int m  = l & 15;     // output-within-tile / C col (cout)
    const int iq = l >> 4;     // cin chunk iq*8..+7 ; C rows iq*4..+3
    const int o0 = (blockIdx.x * 4 + w) * 16;

    __shared__ uint eld[4][384];

    if (o0 >= N) return;       // wave-uniform exit; no barriers in this kernel

    const uint s0 = starts[o0];
    const uint sm = starts[o0 + m];
    const uint se = starts[o0 + m + 1];
    uint total = starts[o0 + 16] - s0;
    if (total > 384) total = 384;
    for (uint t = l; t < total; t += 64)
        eld[w][t] = entries[s0 + t];
    // wave-local fence: all lanes' LDS writes drained before any lane reads
    asm volatile("s_waitcnt lgkmcnt(0) vmcnt(0)" ::: "memory");
    __builtin_amdgcn_sched_barrier(0);

    // per-lane insertion sort of its list (groups by k; deterministic order)
    if (iq == 0) {
        const uint a = sm - s0, bnd = se - s0;
        for (uint i = a + 1; i < bnd; ++i) {
            uint key = eld[w][i];
            uint j = i;
            while (j > a && eld[w][j - 1] > key) { eld[w][j] = eld[w][j - 1]; --j; }
            eld[w][j] = key;
        }
    }
    asm volatile("s_waitcnt lgkmcnt(0)" ::: "memory");
    __builtin_amdgcn_sched_barrier(0);

    f32x4 c0 = {0.f, 0.f, 0.f, 0.f};
    f32x4 c1 = {0.f, 0.f, 0.f, 0.f};

    uint q = sm - s0;
    const uint e = se - s0;
    uint ent = (q < e) ? eld[w][q] : 0xFFFFFFFFu;

    for (int k = 0; k < 27; ++k) {
        const ushort* wk = Wt + (k << 10);
        U4S8 b0, b1;
        b0.u = *(const uint4*)(wk + m * 32 + iq * 8);
        b1.u = *(const uint4*)(wk + (m + 16) * 32 + iq * 8);

        float a0=0.f,a1=0.f,a2=0.f,a3=0.f,a4=0.f,a5=0.f,a6=0.f,a7=0.f;
        bool got = false;
        while ((ent >> 19) == (uint)k) {
            got = true;
            const uint pi = ent & 0x7FFFFu;
            uint4 v = *(const uint4*)(xb + (size_t)pi * 32 + iq * 8);
            a0 += __uint_as_float(v.x << 16);
            a1 += __uint_as_float(v.x & 0xFFFF0000u);
            a2 += __uint_as_float(v.y << 16);
            a3 += __uint_as_float(v.y & 0xFFFF0000u);
            a4 += __uint_as_float(v.z << 16);
            a5 += __uint_as_float(v.z & 0xFFFF0000u);
            a6 += __uint_as_float(v.w << 16);
            a7 += __uint_as_float(v.w & 0xFFFF0000u);
            ++q;
            ent = (q < e) ? eld[w][q] : 0xFFFFFFFFu;
        }
        if (__any(got)) {
            U4S8 af;
            asm volatile("v_cvt_pk_bf16_f32 %0, %1, %2" : "=v"(af.u.x) : "v"(a0), "v"(a1));
            asm volatile("v_cvt_pk_bf16_f32 %0, %1, %2" : "=v"(af.u.y) : "v"(a2), "v"(a3));
            asm volatile("v_cvt_pk_bf16_f32 %0, %1, %2" : "=v"(af.u.z) : "v"(a4), "v"(a5));
            asm volatile("v_cvt_pk_bf16_f32 %0, %1, %2" : "=v"(af.u.w) : "v"(a6), "v"(a7));
            c0 = __builtin_amdgcn_mfma_f32_16x16x32_bf16(af.s, b0.s, c0, 0, 0, 0);
            c1 = __builtin_amdgcn_mfma_f32_16x16x32_bf16(af.s, b1.s, c1, 0, 0, 0);
        }
    }

#pragma unroll
    for (int j = 0; j < 4; ++j) {
        const long ro = (long)(o0 + iq * 4 + j) * 32;
        if (FINAL) {
            outf[ro + m]      = c0[j] + iden[ro + m];
            outf[ro + 16 + m] = c1[j] + iden[ro + 16 + m];
        } else {
            outb[ro + m]      = f2bf(c0[j]);
            outb[ro + 16 + m] = f2bf(c1[j]);
        }
    }
}

// ---------------- downsample scatter-mean ----------------
__global__ void ds_scatter(const float* __restrict__ xyz,
                           const int* __restrict__ batch,
                           const int* __restrict__ din,
                           const int* __restrict__ dout,
                           float* __restrict__ dsum, float* __restrict__ dcnt,
                           int P2n) {
    int p = blockIdx.x * 256 + threadIdx.x;
    if (p >= P2n) return;
    int i = din[p];
    if (i < 0) return;
    int o = dout[p];
    atomicAdd(&dsum[o * 4 + 0], xyz[(long)i * 3 + 0]);
    atomicAdd(&dsum[o * 4 + 1], xyz[(long)i * 3 + 1]);
    atomicAdd(&dsum[o * 4 + 2], xyz[(long)i * 3 + 2]);
    atomicAdd(&dsum[o * 4 + 3], (float)batch[i]);
    atomicAdd(&dcnt[o], 1.0f);
}

__global__ void ds_finalize(const float* __restrict__ dsum,
                            const float* __restrict__ dcnt,
                            float* __restrict__ out_xyz,
                            float* __restrict__ out_batch, int M) {
    int o = blockIdx.x * 256 + threadIdx.x;
    if (o >= M) return;
    float c = fmaxf(dcnt[o], 1.0f);
    float inv = 1.0f / c;
    out_xyz[(long)o * 3 + 0] = dsum[o * 4 + 0] * inv;
    out_xyz[(long)o * 3 + 1] = dsum[o * 4 + 1] * inv;
    out_xyz[(long)o * 3 + 2] = dsum[o * 4 + 2] * inv;
    out_batch[o] = dsum[o * 4 + 3] * inv;
}

extern "C" void kernel_launch(void* const* d_in, const int* in_sizes, int n_in,
                              void* d_out, int out_size, void* d_ws, size_t ws_size,
                              hipStream_t stream) {
    const float* feats = (const float*)d_in[0];
    const float* xyz   = (const float*)d_in[1];
    const int*   batch = (const int*)d_in[2];
    const int*   pin   = (const int*)d_in[3];
    const int*   pout  = (const int*)d_in[4];
    const int*   dsin  = (const int*)d_in[5];
    const int*   dsout = (const int*)d_in[6];
    const float* W1    = (const float*)d_in[7];
    const float* W2    = (const float*)d_in[8];

    const int N   = in_sizes[0] / 32;
    const int K   = 27;
    const int P   = in_sizes[3] / K;
    const int KP  = K * P;
    const int P2n = in_sizes[5];
    const int M   = (out_size - N * 32) / 4;
    const int nbuck = (N + 127) >> BKT_SH;       // 2344 for N=300000
    const int chunk = (KP + CBLK - 1) / CBLK;    // 15821 <= LDSCAP

    auto align256 = [](size_t x) { return (x + 255) & ~(size_t)255; };
    char* base = (char*)d_ws;
    size_t off = 0;
    float* stats1 = (float*)(base + off); off += 256;
    float* stats2 = (float*)(base + off); off += 256;
    float* dsum   = (float*)(base + off); off += (size_t)M * 16;
    float* dcnt   = (float*)(base + off); off = align256(off + (size_t)M * 4);
    const size_t zero_end = off;
    uint* cntmat  = (uint*)(base + off);  off = align256(off + (size_t)CBLK * nbuck * 4);
    uint* btot    = (uint*)(base + off);  off = align256(off + (size_t)nbuck * 4);
    uint* bbase   = (uint*)(base + off);  off = align256(off + (size_t)(nbuck + 1) * 4);
    uint* starts  = (uint*)(base + off);  off = align256(off + (size_t)(N + 1) * 4);
    uint* tmp     = (uint*)(base + off);  off = align256(off + (size_t)KP * 4);
    uint* entries = (uint*)(base + off);  off = align256(off + (size_t)KP * 4);
    ushort* Wt1   = (ushort*)(base + off); off = align256(off + 27 * 1024 * 2);
    ushort* Wt2   = (ushort*)(base + off); off = align256(off + 27 * 1024 * 2);
    ushort* xb    = (ushort*)(base + off); off = align256(off + (size_t)(N + 1) * 64);
    ushort* hacc  = (ushort*)(base + off); off = align256(off + (size_t)N * 64);

    hipMemsetAsync(d_ws, 0, zero_end, stream);

    // W -> bf16 transposed + zero row N of xb (merged)
    prep<<<(2 * 27 * 1024 + 32 + 255) / 256, 256, 0, stream>>>(W1, W2, Wt1, Wt2, xb, N);

    // CSR build (atomic-free; shared by both convs)
    p1_count<<<CBLK, 256, 0, stream>>>(pin, pout, cntmat, KP, chunk, nbuck);
    p2_colscan<<<(nbuck + 63) / 64, 256, 0, stream>>>(cntmat, btot, nbuck);
    p3_bucketscan<<<1, 256, 0, stream>>>(btot, bbase, starts, nbuck, N);
    p4_place<<<CBLK, 256, 0, stream>>>(pin, pout, cntmat, bbase, tmp, KP, P, chunk, nbuck);
    p5_fine<<<nbuck, 256, 0, stream>>>(tmp, bbase, entries, starts, N);

    // conv1: bn_relu(feats) -> W1 -> hacc (bf16)
    stats_f32<<<1024, 256, 0, stream>>>(feats, stats1, N * 8);
    bnrelu_f32<<<(N * 4 + 255) / 256, 256, 0, stream>>>(feats, stats1, xb, N * 4, N);
    const int cblocks = (N / 16 + 3) / 4;
    conv_csr<false><<<cblocks, 256, 0, stream>>>(xb, Wt1, starts, entries,
                                                 nullptr, nullptr, hacc, N);

    // conv2: bn_relu(hacc) -> W2 -> out (+ identity feats)
    stats_bf16<<<1024, 256, 0, stream>>>(hacc, stats2, N * 4);
    bnrelu_bf16<<<(N * 4 + 255) / 256, 256, 0, stream>>>(hacc, stats2, xb, N * 4, N);
    float* out = (float*)d_out;
    conv_csr<true><<<cblocks, 256, 0, stream>>>(xb, Wt2, starts, entries,
                                                feats, out, nullptr, N);

    // downsample scatter-mean
    ds_scatter<<<(P2n + 255) / 256, 256, 0, stream>>>(xyz, batch, dsin, dsout,
                                                      dsum, dcnt, P2n);
    ds_finalize<<<(M + 255) / 256, 256, 0, stream>>>(dsum, dcnt,
                                                     out + (size_t)N * 32,
                                                     out + (size_t)N * 32 + (size_t)3 * M,
                                                     M);
}

// Round 12
// 538.362 us; speedup vs baseline: 1.2432x; 1.1462x over previous
//
#include <hip/hip_runtime.h>

#define BN_EPS 1e-4f
#define BKT_SH 7          // 128 outputs per bucket
#define NBUCK_MAX 2560
#define CBLK 1024         // blocks in count/place phases (4 blocks/CU)
#define LDSCAP 4096       // max records per place-block (chunk = 3956)
#define P3CAP 2048        // max records per bucket

typedef __attribute__((ext_vector_type(8))) short short8;   // 8 bf16
typedef __attribute__((ext_vector_type(4))) float f32x4;    // MFMA acc
typedef __attribute__((ext_vector_type(4))) float floatv4;
typedef unsigned int uint;

union U4S8 { uint4 u; short8 s; };

// float -> bf16 bits, round-to-nearest-even
static __device__ __forceinline__ unsigned short f2bf(float f) {
    unsigned u = __float_as_uint(f);
    unsigned r = (u + 0x7FFFu + ((u >> 16) & 1u)) >> 16;
    return (unsigned short)r;
}

// ---------------- BN stats over f32 [N,32]: per-channel sum & sumsq -------
__global__ void stats_f32(const float* __restrict__ x,
                          float* __restrict__ stats, int total4) {
    const int t = threadIdx.x;
    long idx = (long)blockIdx.x * 256 + t;
    const long stride = (long)gridDim.x * 256;
    float s[4] = {0.f, 0.f, 0.f, 0.f}, q[4] = {0.f, 0.f, 0.f, 0.f};
    const floatv4* x4 = (const floatv4*)x;
    for (long e = idx; e < total4; e += stride) {
        floatv4 v = x4[e];
#pragma unroll
        for (int j = 0; j < 4; ++j) { s[j] += v[j]; q[j] += v[j] * v[j]; }
    }
    __shared__ float red[256][4];
#pragma unroll
    for (int j = 0; j < 4; ++j) red[t][j] = s[j];
    __syncthreads();
    if (t < 32) {
        float a = 0.f;
        const int grp = t >> 2, j = t & 3;
#pragma unroll
        for (int m = 0; m < 32; ++m) a += red[grp + 8 * m][j];
        atomicAdd(&stats[t], a);
    }
    __syncthreads();
#pragma unroll
    for (int j = 0; j < 4; ++j) red[t][j] = q[j];
    __syncthreads();
    if (t < 32) {
        float a = 0.f;
        const int grp = t >> 2, j = t & 3;
#pragma unroll
        for (int m = 0; m < 32; ++m) a += red[grp + 8 * m][j];
        atomicAdd(&stats[32 + t], a);
    }
}

// ---------------- BN stats over bf16 [N,32] ----------------
__global__ void stats_bf16(const ushort* __restrict__ x,
                           float* __restrict__ stats, int n8) {
    const int t = threadIdx.x;
    long idx = (long)blockIdx.x * 256 + t;
    const long stride = (long)gridDim.x * 256;
    float s[8] = {0}, q[8] = {0};
    const uint4* x8 = (const uint4*)x;
    for (long e = idx; e < n8; e += stride) {
        uint4 v = x8[e];
        uint w0 = v.x, w1 = v.y, w2 = v.z, w3 = v.w;
        float f0 = __uint_as_float(w0 << 16), f1 = __uint_as_float(w0 & 0xFFFF0000u);
        float f2 = __uint_as_float(w1 << 16), f3 = __uint_as_float(w1 & 0xFFFF0000u);
        float f4 = __uint_as_float(w2 << 16), f5 = __uint_as_float(w2 & 0xFFFF0000u);
        float f6 = __uint_as_float(w3 << 16), f7 = __uint_as_float(w3 & 0xFFFF0000u);
        s[0]+=f0; q[0]+=f0*f0; s[1]+=f1; q[1]+=f1*f1;
        s[2]+=f2; q[2]+=f2*f2; s[3]+=f3; q[3]+=f3*f3;
        s[4]+=f4; q[4]+=f4*f4; s[5]+=f5; q[5]+=f5*f5;
        s[6]+=f6; q[6]+=f6*f6; s[7]+=f7; q[7]+=f7*f7;
    }
    __shared__ float red[256][8];
#pragma unroll
    for (int j = 0; j < 8; ++j) red[t][j] = s[j];
    __syncthreads();
    if (t < 32) {
        float a = 0.f;
        const int grp = t >> 3, j = t & 7;
#pragma unroll
        for (int m = 0; m < 64; ++m) a += red[grp + 4 * m][j];
        atomicAdd(&stats[t], a);
    }
    __syncthreads();
#pragma unroll
    for (int j = 0; j < 8; ++j) red[t][j] = q[j];
    __syncthreads();
    if (t < 32) {
        float a = 0.f;
        const int grp = t >> 3, j = t & 7;
#pragma unroll
        for (int m = 0; m < 64; ++m) a += red[grp + 4 * m][j];
        atomicAdd(&stats[32 + t], a);
    }
}

// ---------------- bn_relu + cast to bf16 (f32 input) ----------------
__global__ void bnrelu_f32(const float* __restrict__ x,
                           const float* __restrict__ stats,
                           ushort* __restrict__ xb, int n8, int N) {
    int idx = blockIdx.x * 256 + threadIdx.x;
    if (idx >= n8) return;
    const int c0 = (idx & 3) * 8;
    const float invN = 1.0f / (float)N;
    floatv4 v0 = *(const floatv4*)(x + (size_t)idx * 8);
    floatv4 v1 = *(const floatv4*)(x + (size_t)idx * 8 + 4);
    uint r[8];
#pragma unroll
    for (int j = 0; j < 8; ++j) {
        const int c = c0 + j;
        float mu = stats[c] * invN;
        float var = stats[32 + c] * invN - mu * mu;
        float rs = rsqrtf(var + BN_EPS);
        float f = (j < 4) ? v0[j] : v1[j - 4];
        float xn = fmaxf((f - mu) * rs, 0.f);
        r[j] = (uint)f2bf(xn);
    }
    uint4 o;
    o.x = r[0] | (r[1] << 16); o.y = r[2] | (r[3] << 16);
    o.z = r[4] | (r[5] << 16); o.w = r[6] | (r[7] << 16);
    *(uint4*)(xb + (size_t)idx * 8) = o;
}

// ---------------- bn_relu + cast to bf16 (bf16 input) ----------------
__global__ void bnrelu_bf16(const ushort* __restrict__ h,
                            const float* __restrict__ stats,
                            ushort* __restrict__ xb, int n8, int N) {
    int idx = blockIdx.x * 256 + threadIdx.x;
    if (idx >= n8) return;
    const int c0 = (idx & 3) * 8;
    const float invN = 1.0f / (float)N;
    uint4 v = *(const uint4*)(h + (size_t)idx * 8);
    uint w[4] = {v.x, v.y, v.z, v.w};
    uint r[8];
#pragma unroll
    for (int j = 0; j < 8; ++j) {
        const int c = c0 + j;
        float mu = stats[c] * invN;
        float var = stats[32 + c] * invN - mu * mu;
        float rs = rsqrtf(var + BN_EPS);
        uint bits = (j & 1) ? (w[j >> 1] & 0xFFFF0000u) : (w[j >> 1] << 16);
        float f = __uint_as_float(bits);
        float xn = fmaxf((f - mu) * rs, 0.f);
        r[j] = (uint)f2bf(xn);
    }
    uint4 o;
    o.x = r[0] | (r[1] << 16); o.y = r[2] | (r[3] << 16);
    o.z = r[4] | (r[5] << 16); o.w = r[6] | (r[7] << 16);
    *(uint4*)(xb + (size_t)idx * 8) = o;
}

// ------- prep: W1,W2 -> bf16 transposed; zero row N of xb (merged) --------
__global__ void prep(const float* __restrict__ W1, const float* __restrict__ W2,
                     ushort* __restrict__ Wt1, ushort* __restrict__ Wt2,
                     ushort* __restrict__ xb, int N) {
    int idx = blockIdx.x * 256 + threadIdx.x;
    if (idx < 27 * 1024) {
        int k = idx >> 10, r = idx & 1023, co = r >> 5, ci = r & 31;
        Wt1[(k << 10) + (co << 5) + ci] = f2bf(W1[(k << 10) + (ci << 5) + co]);
    } else if (idx < 2 * 27 * 1024) {
        int i2 = idx - 27 * 1024;
        int k = i2 >> 10, r = i2 & 1023, co = r >> 5, ci = r & 31;
        Wt2[(k << 10) + (co << 5) + ci] = f2bf(W2[(k << 10) + (ci << 5) + co]);
    } else if (idx < 2 * 27 * 1024 + 32) {
        xb[(size_t)N * 32 + (idx - 2 * 27 * 1024)] = 0;
    }
}

// ============ CSR build: atomic-free MSD bucket sort ============
// bucket = pout >> 7 (128 outputs each). Record payload = (k<<19)|pin (24b).

__global__ void p1_count(const int* __restrict__ pin, const int* __restrict__ pout,
                         uint* __restrict__ cntmat, int KP, int chunk, int nbuck) {
    __shared__ uint H[NBUCK_MAX];
    const int t = threadIdx.x;
    for (int i = t; i < nbuck; i += 256) H[i] = 0;
    __syncthreads();
    const int r0 = blockIdx.x * chunk;
    const int r1 = min(KP, r0 + chunk);
    for (int r = r0 + t; r < r1; r += 256)
        if (pin[r] >= 0) atomicAdd(&H[((uint)pout[r]) >> BKT_SH], 1u);
    __syncthreads();
    uint* row = cntmat + (size_t)blockIdx.x * nbuck;
    for (int i = t; i < nbuck; i += 256) row[i] = H[i];
}

// p2: per-bucket exclusive scan over CBLK rows. Block = 16 buckets x 16
// segments of (CBLK/16) rows. 16 consecutive buckets = 64B per 16 lanes.
__global__ void p2_colscan(uint* __restrict__ cntmat, uint* __restrict__ btot,
                           int nbuck) {
    const int tid = threadIdx.x;
    const int bi  = tid & 15;
    const int seg = tid >> 4;            // 0..15
    const int b   = blockIdx.x * 16 + bi;
    const int rpseg = CBLK / 16;         // 64 rows per segment
    const bool valid = (b < nbuck);
    uint s = 0;
    if (valid) {
        for (int u = 0; u < rpseg; ++u)
            s += cntmat[(size_t)(seg * rpseg + u) * nbuck + b];
    }
    __shared__ uint ss[16][16];
    ss[seg][bi] = s;
    __syncthreads();
    uint pre = 0;
    for (int g = 0; g < seg; ++g) pre += ss[g][bi];
    if (valid && seg == 15) btot[b] = pre + s;
    if (valid) {
        uint run = pre;
        for (int u = 0; u < rpseg; ++u) {
            size_t idx = (size_t)(seg * rpseg + u) * nbuck + b;
            uint v = cntmat[idx];
            cntmat[idx] = run;           // exclusive over blocks
            run += v;
        }
    }
}

__global__ void p3_bucketscan(const uint* __restrict__ btot, uint* __restrict__ bbase,
                              uint* __restrict__ starts, int nbuck, int N) {
    const int t = threadIdx.x;
    __shared__ uint part[256];
    uint loc[10]; uint s = 0;
#pragma unroll
    for (int u = 0; u < 10; ++u) {
        int i = t * 10 + u;
        loc[u] = (i < nbuck) ? btot[i] : 0;
        s += loc[u];
    }
    part[t] = s;
    __syncthreads();
    for (int off = 1; off < 256; off <<= 1) {
        uint y = (t >= off) ? part[t - off] : 0;
        __syncthreads();
        part[t] += y;
        __syncthreads();
    }
    uint run = part[t] - s;
#pragma unroll
    for (int u = 0; u < 10; ++u) {
        int i = t * 10 + u;
        if (i < nbuck) { bbase[i] = run; run += loc[u]; }
    }
    if (t == 255) { bbase[nbuck] = run; starts[N] = run; }
}

// phase 4: counting-sort block's records by bucket in LDS, write bucket runs.
// bucket id stored in u16 sidecar at placement -> no binary search at write.
__global__ __launch_bounds__(256)
void p4_place(const int* __restrict__ pin, const int* __restrict__ pout,
              const uint* __restrict__ cntmat, const uint* __restrict__ bbase,
              uint* __restrict__ tmp, int KP, int P, int chunk, int nbuck) {
    __shared__ uint recs[LDSCAP];
    __shared__ ushort bof[LDSCAP];
    __shared__ uint H[NBUCK_MAX + 1];
    __shared__ uint C[NBUCK_MAX];
    __shared__ uint part[256];
    const int t = threadIdx.x;
    const int j = blockIdx.x;
    for (int i = t; i < nbuck; i += 256) H[i] = 0;
    __syncthreads();
    const int r0 = j * chunk;
    const int r1 = min(KP, r0 + chunk);
    for (int r = r0 + t; r < r1; r += 256)
        if (pin[r] >= 0) atomicAdd(&H[((uint)pout[r]) >> BKT_SH], 1u);
    __syncthreads();
    uint loc[10]; uint s = 0;
#pragma unroll
    for (int u = 0; u < 10; ++u) {
        int i = t * 10 + u;
        loc[u] = (i < nbuck) ? H[i] : 0;
        s += loc[u];
    }
    __syncthreads();
    part[t] = s;
    __syncthreads();
    for (int off = 1; off < 256; off <<= 1) {
        uint y = (t >= off) ? part[t - off] : 0;
        __syncthreads();
        part[t] += y;
        __syncthreads();
    }
    uint run = part[t] - s;
#pragma unroll
    for (int u = 0; u < 10; ++u) {
        int i = t * 10 + u;
        if (i < nbuck) { uint c = loc[u]; H[i] = run; run += c; }
    }
    if (t == 255) H[nbuck] = run;
    __syncthreads();
    for (int i = t; i < nbuck; i += 256) C[i] = H[i];   // cursors
    __syncthreads();
    for (int r = r0 + t; r < r1; r += 256) {
        int ii = pin[r];
        if (ii < 0) continue;
        uint po = (uint)pout[r];
        uint b = po >> BKT_SH;
        uint k = (uint)r / (uint)P;
        uint pos = atomicAdd(&C[b], 1u);
        recs[pos] = ((po & 127u) << 24) | (k << 19) | (uint)ii;
        bof[pos] = (ushort)b;
    }
    __syncthreads();
    const uint tot = H[nbuck];
    for (int i = t; i < nbuck; i += 256)
        C[i] = bbase[i] + cntmat[(size_t)j * nbuck + i] - H[i];  // dest bias
    __syncthreads();
    for (uint sdx = t; sdx < tot; sdx += 256) {
        uint b = (uint)bof[sdx];
        tmp[C[b] + sdx] = recs[sdx];
    }
}

// phase 5: per-bucket counting-sort by output -> starts + entries.
// entries MAY ALIAS tmp (whole range staged into LDS before any write),
// hence no __restrict__ on tmp/entries.
__global__ void p5_fine(const uint* tmp, const uint* __restrict__ bbase,
                        uint* entries, uint* __restrict__ starts, int N) {
    __shared__ uint recs[P3CAP];
    __shared__ uint cnt[128];
    __shared__ uint curl[128];
    const int b = blockIdx.x;
    const int t = threadIdx.x;
    const uint e0 = bbase[b];
    uint nrec = bbase[b + 1] - e0;
    if (nrec > P3CAP) nrec = P3CAP;
    for (uint s = t; s < nrec; s += 256) recs[s] = tmp[e0 + s];
    if (t < 128) { cnt[t] = 0; curl[t] = 0; }
    __syncthreads();
    for (uint s = t; s < nrec; s += 256) atomicAdd(&cnt[recs[s] >> 24], 1u);
    __syncthreads();
    uint orig = (t < 128) ? cnt[t] : 0;
    for (int off = 1; off < 128; off <<= 1) {
        uint y = (t < 128 && t >= off) ? cnt[t - off] : 0;
        __syncthreads();
        if (t < 128) cnt[t] += y;
        __syncthreads();
    }
    if (t < 128) cnt[t] -= orig;
    __syncthreads();
    const int o0 = b << BKT_SH;
    if (t < 128 && o0 + t < N) starts[o0 + t] = e0 + cnt[t];
    for (uint s = t; s < nrec; s += 256) {
        uint lo = recs[s] >> 24;
        uint idx = atomicAdd(&curl[lo], 1u);
        entries[e0 + cnt[lo] + idx] = recs[s] & 0x00FFFFFFu;
    }
}

// ------- CSR-gather MFMA conv: wave-independent (NO block barriers) -------
// (byte-identical logic to round-11 passing version)
template <bool FINAL>
__global__ void conv_csr(const ushort* __restrict__ xb,   // [N+1][32], row N = 0
                         const ushort* __restrict__ Wt,   // [27][32 cout][32 cin]
                         const uint* __restrict__ starts,
                         const uint* __restrict__ entries,
                         const float* __restrict__ iden,
                         float* __restrict__ outf,
                         ushort* __restrict__ outb,
                         int N) {
    const int w  = threadIdx.x >> 6;
    const int l  = threadIdx.x & 63;
    const int m  = l & 15;     // output-within-tile / C col (cout)
    const int iq = l >> 4;     // cin chunk iq*8..+7 ; C rows iq*4..+3
    const int o0 = (blockIdx.x * 4 + w) * 16;

    __shared__ uint eld[4][384];

    if (o0 >= N) return;       // wave-uniform exit; no barriers in this kernel

    const uint s0 = starts[o0];
    const uint sm = starts[o0 + m];
    const uint se = starts[o0 + m + 1];
    uint total = starts[o0 + 16] - s0;
    if (total > 384) total = 384;
    for (uint t = l; t < total; t += 64)
        eld[w][t] = entries[s0 + t];
    asm volatile("s_waitcnt lgkmcnt(0) vmcnt(0)" ::: "memory");
    __builtin_amdgcn_sched_barrier(0);

    if (iq == 0) {
        const uint a = sm - s0, bnd = se - s0;
        for (uint i = a + 1; i < bnd; ++i) {
            uint key = eld[w][i];
            uint j = i;
            while (j > a && eld[w][j - 1] > key) { eld[w][j] = eld[w][j - 1]; --j; }
            eld[w][j] = key;
        }
    }
    asm volatile("s_waitcnt lgkmcnt(0)" ::: "memory");
    __builtin_amdgcn_sched_barrier(0);

    f32x4 c0 = {0.f, 0.f, 0.f, 0.f};
    f32x4 c1 = {0.f, 0.f, 0.f, 0.f};

    uint q = sm - s0;
    const uint e = se - s0;
    uint ent = (q < e) ? eld[w][q] : 0xFFFFFFFFu;

    for (int k = 0; k < 27; ++k) {
        const ushort* wk = Wt + (k << 10);
        U4S8 b0, b1;
        b0.u = *(const uint4*)(wk + m * 32 + iq * 8);
        b1.u = *(const uint4*)(wk + (m + 16) * 32 + iq * 8);

        float a0=0.f,a1=0.f,a2=0.f,a3=0.f,a4=0.f,a5=0.f,a6=0.f,a7=0.f;
        bool got = false;
        while ((ent >> 19) == (uint)k) {
            got = true;
            const uint pi = ent & 0x7FFFFu;
            uint4 v = *(const uint4*)(xb + (size_t)pi * 32 + iq * 8);
            a0 += __uint_as_float(v.x << 16);
            a1 += __uint_as_float(v.x & 0xFFFF0000u);
            a2 += __uint_as_float(v.y << 16);
            a3 += __uint_as_float(v.y & 0xFFFF0000u);
            a4 += __uint_as_float(v.z << 16);
            a5 += __uint_as_float(v.z & 0xFFFF0000u);
            a6 += __uint_as_float(v.w << 16);
            a7 += __uint_as_float(v.w & 0xFFFF0000u);
            ++q;
            ent = (q < e) ? eld[w][q] : 0xFFFFFFFFu;
        }
        if (__any(got)) {
            U4S8 af;
            asm volatile("v_cvt_pk_bf16_f32 %0, %1, %2" : "=v"(af.u.x) : "v"(a0), "v"(a1));
            asm volatile("v_cvt_pk_bf16_f32 %0, %1, %2" : "=v"(af.u.y) : "v"(a2), "v"(a3));
            asm volatile("v_cvt_pk_bf16_f32 %0, %1, %2" : "=v"(af.u.z) : "v"(a4), "v"(a5));
            asm volatile("v_cvt_pk_bf16_f32 %0, %1, %2" : "=v"(af.u.w) : "v"(a6), "v"(a7));
            c0 = __builtin_amdgcn_mfma_f32_16x16x32_bf16(af.s, b0.s, c0, 0, 0, 0);
            c1 = __builtin_amdgcn_mfma_f32_16x16x32_bf16(af.s, b1.s, c1, 0, 0, 0);
        }
    }

#pragma unroll
    for (int j = 0; j < 4; ++j) {
        const long ro = (long)(o0 + iq * 4 + j) * 32;
        if (FINAL) {
            outf[ro + m]      = c0[j] + iden[ro + m];
            outf[ro + 16 + m] = c1[j] + iden[ro + 16 + m];
        } else {
            outb[ro + m]      = f2bf(c0[j]);
            outb[ro + 16 + m] = f2bf(c1[j]);
        }
    }
}

// ---------------- downsample scatter-mean (clustered 32B accumulators) ----
__global__ void ds_scatter(const float* __restrict__ xyz,
                           const int* __restrict__ batch,
                           const int* __restrict__ din,
                           const int* __restrict__ dout,
                           float* __restrict__ dsum,   // [M][8]: x,y,z,b,cnt
                           int P2n) {
    int p = blockIdx.x * 256 + threadIdx.x;
    if (p >= P2n) return;
    int i = din[p];
    if (i < 0) return;
    int o = dout[p];
    float* d = dsum + (size_t)o * 8;
    atomicAdd(&d[0], xyz[(long)i * 3 + 0]);
    atomicAdd(&d[1], xyz[(long)i * 3 + 1]);
    atomicAdd(&d[2], xyz[(long)i * 3 + 2]);
    atomicAdd(&d[3], (float)batch[i]);
    atomicAdd(&d[4], 1.0f);
}

__global__ void ds_finalize(const float* __restrict__ dsum,
                            float* __restrict__ out_xyz,
                            float* __restrict__ out_batch, int M) {
    int o = blockIdx.x * 256 + threadIdx.x;
    if (o >= M) return;
    const float* d = dsum + (size_t)o * 8;
    float c = fmaxf(d[4], 1.0f);
    float inv = 1.0f / c;
    out_xyz[(long)o * 3 + 0] = d[0] * inv;
    out_xyz[(long)o * 3 + 1] = d[1] * inv;
    out_xyz[(long)o * 3 + 2] = d[2] * inv;
    out_batch[o] = d[3] * inv;
}

extern "C" void kernel_launch(void* const* d_in, const int* in_sizes, int n_in,
                              void* d_out, int out_size, void* d_ws, size_t ws_size,
                              hipStream_t stream) {
    const float* feats = (const float*)d_in[0];
    const float* xyz   = (const float*)d_in[1];
    const int*   batch = (const int*)d_in[2];
    const int*   pin   = (const int*)d_in[3];
    const int*   pout  = (const int*)d_in[4];
    const int*   dsin  = (const int*)d_in[5];
    const int*   dsout = (const int*)d_in[6];
    const float* W1    = (const float*)d_in[7];
    const float* W2    = (const float*)d_in[8];

    const int N   = in_sizes[0] / 32;
    const int K   = 27;
    const int P   = in_sizes[3] / K;
    const int KP  = K * P;
    const int P2n = in_sizes[5];
    const int M   = (out_size - N * 32) / 4;
    const int nbuck = (N + 127) >> BKT_SH;       // 2344 for N=300000
    const int chunk = (KP + CBLK - 1) / CBLK;    // 3956 <= LDSCAP

    auto align256 = [](size_t x) { return (x + 255) & ~(size_t)255; };
    char* base = (char*)d_ws;
    size_t off = 0;
    float* stats1 = (float*)(base + off); off += 256;
    float* stats2 = (float*)(base + off); off += 256;
    float* dsum   = (float*)(base + off); off = align256(off + (size_t)M * 32);
    const size_t zero_end = off;
    uint* cntmat  = (uint*)(base + off);  off = align256(off + (size_t)CBLK * nbuck * 4);
    uint* btot    = (uint*)(base + off);  off = align256(off + (size_t)nbuck * 4);
    uint* bbase   = (uint*)(base + off);  off = align256(off + (size_t)(nbuck + 1) * 4);
    uint* starts  = (uint*)(base + off);  off = align256(off + (size_t)(N + 1) * 4);
    uint* tmp     = (uint*)(base + off);  off = align256(off + (size_t)KP * 4);
    uint* entries = tmp;                  // built in place by p5
    ushort* Wt1   = (ushort*)(base + off); off = align256(off + 27 * 1024 * 2);
    ushort* Wt2   = (ushort*)(base + off); off = align256(off + 27 * 1024 * 2);
    ushort* xb    = (ushort*)(base + off); off = align256(off + (size_t)(N + 1) * 64);
    ushort* hacc  = (ushort*)(base + off); off = align256(off + (size_t)N * 64);

    hipMemsetAsync(d_ws, 0, zero_end, stream);

    // W -> bf16 transposed + zero row N of xb (merged)
    prep<<<(2 * 27 * 1024 + 32 + 255) / 256, 256, 0, stream>>>(W1, W2, Wt1, Wt2, xb, N);

    // CSR build (atomic-free; shared by both convs)
    p1_count<<<CBLK, 256, 0, stream>>>(pin, pout, cntmat, KP, chunk, nbuck);
    p2_colscan<<<(nbuck + 15) / 16, 256, 0, stream>>>(cntmat, btot, nbuck);
    p3_bucketscan<<<1, 256, 0, stream>>>(btot, bbase, starts, nbuck, N);
    p4_place<<<CBLK, 256, 0, stream>>>(pin, pout, cntmat, bbase, tmp, KP, P, chunk, nbuck);
    p5_fine<<<nbuck, 256, 0, stream>>>(tmp, bbase, entries, starts, N);

    // conv1: bn_relu(feats) -> W1 -> hacc (bf16)
    stats_f32<<<1024, 256, 0, stream>>>(feats, stats1, N * 8);
    bnrelu_f32<<<(N * 4 + 255) / 256, 256, 0, stream>>>(feats, stats1, xb, N * 4, N);
    const int cblocks = (N / 16 + 3) / 4;
    conv_csr<false><<<cblocks, 256, 0, stream>>>(xb, Wt1, starts, entries,
                                                 nullptr, nullptr, hacc, N);

    // conv2: bn_relu(hacc) -> W2 -> out (+ identity feats)
    stats_bf16<<<1024, 256, 0, stream>>>(hacc, stats2, N * 4);
    bnrelu_bf16<<<(N * 4 + 255) / 256, 256, 0, stream>>>(hacc, stats2, xb, N * 4, N);
    float* out = (float*)d_out;
    conv_csr<true><<<cblocks, 256, 0, stream>>>(xb, Wt2, starts, entries,
                                                feats, out, nullptr, N);

    // downsample scatter-mean
    ds_scatter<<<(P2n + 255) / 256, 256, 0, stream>>>(xyz, batch, dsin, dsout,
                                                      dsum, P2n);
    ds_finalize<<<(M + 255) / 256, 256, 0, stream>>>(dsum,
                                                     out + (size_t)N * 32,
                                                     out + (size_t)N * 32 + (size_t)3 * M,
                                                     M);
}

// Round 13
// 502.179 us; speedup vs baseline: 1.3328x; 1.0721x over previous
//
#include <hip/hip_runtime.h>

#define BN_EPS 1e-4f
#define BKT_SH 7          // 128 outputs per bucket
#define NBUCK_MAX 2560
#define CBLK 1024         // blocks in count/place phases (4 blocks/CU)
#define LDSCAP 4096       // max records per place-block (chunk = 3956)
#define P3CAP 2048        // max records per bucket

typedef __attribute__((ext_vector_type(8))) short short8;   // 8 bf16
typedef __attribute__((ext_vector_type(4))) float f32x4;    // MFMA acc
typedef __attribute__((ext_vector_type(4))) float floatv4;
typedef unsigned int uint;

union U4S8 { uint4 u; short8 s; };

// float -> bf16 bits, round-to-nearest-even
static __device__ __forceinline__ unsigned short f2bf(float f) {
    unsigned u = __float_as_uint(f);
    unsigned r = (u + 0x7FFFu + ((u >> 16) & 1u)) >> 16;
    return (unsigned short)r;
}

// ---------------- BN stats over f32 [N,32]: per-channel sum & sumsq -------
__global__ void stats_f32(const float* __restrict__ x,
                          float* __restrict__ stats, int total4) {
    const int t = threadIdx.x;
    long idx = (long)blockIdx.x * 256 + t;
    const long stride = (long)gridDim.x * 256;
    float s[4] = {0.f, 0.f, 0.f, 0.f}, q[4] = {0.f, 0.f, 0.f, 0.f};
    const floatv4* x4 = (const floatv4*)x;
    for (long e = idx; e < total4; e += stride) {
        floatv4 v = x4[e];
#pragma unroll
        for (int j = 0; j < 4; ++j) { s[j] += v[j]; q[j] += v[j] * v[j]; }
    }
    __shared__ float red[256][4];
#pragma unroll
    for (int j = 0; j < 4; ++j) red[t][j] = s[j];
    __syncthreads();
    if (t < 32) {
        float a = 0.f;
        const int grp = t >> 2, j = t & 3;
#pragma unroll
        for (int m = 0; m < 32; ++m) a += red[grp + 8 * m][j];
        atomicAdd(&stats[t], a);
    }
    __syncthreads();
#pragma unroll
    for (int j = 0; j < 4; ++j) red[t][j] = q[j];
    __syncthreads();
    if (t < 32) {
        float a = 0.f;
        const int grp = t >> 2, j = t & 3;
#pragma unroll
        for (int m = 0; m < 32; ++m) a += red[grp + 8 * m][j];
        atomicAdd(&stats[32 + t], a);
    }
}

// ---------------- BN stats over bf16 [N,32] ----------------
__global__ void stats_bf16(const ushort* __restrict__ x,
                           float* __restrict__ stats, int n8) {
    const int t = threadIdx.x;
    long idx = (long)blockIdx.x * 256 + t;
    const long stride = (long)gridDim.x * 256;
    float s[8] = {0}, q[8] = {0};
    const uint4* x8 = (const uint4*)x;
    for (long e = idx; e < n8; e += stride) {
        uint4 v = x8[e];
        uint w0 = v.x, w1 = v.y, w2 = v.z, w3 = v.w;
        float f0 = __uint_as_float(w0 << 16), f1 = __uint_as_float(w0 & 0xFFFF0000u);
        float f2 = __uint_as_float(w1 << 16), f3 = __uint_as_float(w1 & 0xFFFF0000u);
        float f4 = __uint_as_float(w2 << 16), f5 = __uint_as_float(w2 & 0xFFFF0000u);
        float f6 = __uint_as_float(w3 << 16), f7 = __uint_as_float(w3 & 0xFFFF0000u);
        s[0]+=f0; q[0]+=f0*f0; s[1]+=f1; q[1]+=f1*f1;
        s[2]+=f2; q[2]+=f2*f2; s[3]+=f3; q[3]+=f3*f3;
        s[4]+=f4; q[4]+=f4*f4; s[5]+=f5; q[5]+=f5*f5;
        s[6]+=f6; q[6]+=f6*f6; s[7]+=f7; q[7]+=f7*f7;
    }
    __shared__ float red[256][8];
#pragma unroll
    for (int j = 0; j < 8; ++j) red[t][j] = s[j];
    __syncthreads();
    if (t < 32) {
        float a = 0.f;
        const int grp = t >> 3, j = t & 7;
#pragma unroll
        for (int m = 0; m < 64; ++m) a += red[grp + 4 * m][j];
        atomicAdd(&stats[t], a);
    }
    __syncthreads();
#pragma unroll
    for (int j = 0; j < 8; ++j) red[t][j] = q[j];
    __syncthreads();
    if (t < 32) {
        float a = 0.f;
        const int grp = t >> 3, j = t & 7;
#pragma unroll
        for (int m = 0; m < 64; ++m) a += red[grp + 4 * m][j];
        atomicAdd(&stats[32 + t], a);
    }
}

// ---------------- bn_relu + cast to bf16 (f32 input) ----------------
__global__ void bnrelu_f32(const float* __restrict__ x,
                           const float* __restrict__ stats,
                           ushort* __restrict__ xb, int n8, int N) {
    int idx = blockIdx.x * 256 + threadIdx.x;
    if (idx >= n8) return;
    const int c0 = (idx & 3) * 8;
    const float invN = 1.0f / (float)N;
    floatv4 v0 = *(const floatv4*)(x + (size_t)idx * 8);
    floatv4 v1 = *(const floatv4*)(x + (size_t)idx * 8 + 4);
    uint r[8];
#pragma unroll
    for (int j = 0; j < 8; ++j) {
        const int c = c0 + j;
        float mu = stats[c] * invN;
        float var = stats[32 + c] * invN - mu * mu;
        float rs = rsqrtf(var + BN_EPS);
        float f = (j < 4) ? v0[j] : v1[j - 4];
        float xn = fmaxf((f - mu) * rs, 0.f);
        r[j] = (uint)f2bf(xn);
    }
    uint4 o;
    o.x = r[0] | (r[1] << 16); o.y = r[2] | (r[3] << 16);
    o.z = r[4] | (r[5] << 16); o.w = r[6] | (r[7] << 16);
    *(uint4*)(xb + (size_t)idx * 8) = o;
}

// ---------------- bn_relu + cast to bf16 (bf16 input) ----------------
__global__ void bnrelu_bf16(const ushort* __restrict__ h,
                            const float* __restrict__ stats,
                            ushort* __restrict__ xb, int n8, int N) {
    int idx = blockIdx.x * 256 + threadIdx.x;
    if (idx >= n8) return;
    const int c0 = (idx & 3) * 8;
    const float invN = 1.0f / (float)N;
    uint4 v = *(const uint4*)(h + (size_t)idx * 8);
    uint w[4] = {v.x, v.y, v.z, v.w};
    uint r[8];
#pragma unroll
    for (int j = 0; j < 8; ++j) {
        const int c = c0 + j;
        float mu = stats[c] * invN;
        float var = stats[32 + c] * invN - mu * mu;
        float rs = rsqrtf(var + BN_EPS);
        uint bits = (j & 1) ? (w[j >> 1] & 0xFFFF0000u) : (w[j >> 1] << 16);
        float f = __uint_as_float(bits);
        float xn = fmaxf((f - mu) * rs, 0.f);
        r[j] = (uint)f2bf(xn);
    }
    uint4 o;
    o.x = r[0] | (r[1] << 16); o.y = r[2] | (r[3] << 16);
    o.z = r[4] | (r[5] << 16); o.w = r[6] | (r[7] << 16);
    *(uint4*)(xb + (size_t)idx * 8) = o;
}

// ------- prep: W1,W2 -> bf16 transposed; zero row N of xb (merged) --------
__global__ void prep(const float* __restrict__ W1, const float* __restrict__ W2,
                     ushort* __restrict__ Wt1, ushort* __restrict__ Wt2,
                     ushort* __restrict__ xb, int N) {
    int idx = blockIdx.x * 256 + threadIdx.x;
    if (idx < 27 * 1024) {
        int k = idx >> 10, r = idx & 1023, co = r >> 5, ci = r & 31;
        Wt1[(k << 10) + (co << 5) + ci] = f2bf(W1[(k << 10) + (ci << 5) + co]);
    } else if (idx < 2 * 27 * 1024) {
        int i2 = idx - 27 * 1024;
        int k = i2 >> 10, r = i2 & 1023, co = r >> 5, ci = r & 31;
        Wt2[(k << 10) + (co << 5) + ci] = f2bf(W2[(k << 10) + (ci << 5) + co]);
    } else if (idx < 2 * 27 * 1024 + 32) {
        xb[(size_t)N * 32 + (idx - 2 * 27 * 1024)] = 0;
    }
}

// ============ CSR build: atomic-free MSD bucket sort (shape-generic) ======
// bucket = pout >> 7. Record payload = (k<<19)|pin (24b). Used for BOTH the
// conv pairs (KP=27*P) and the downsample pairs (KP=P2, K=1 -> k=0).

__global__ void p1_count(const int* __restrict__ pin, const int* __restrict__ pout,
                         uint* __restrict__ cntmat, int KP, int chunk, int nbuck) {
    __shared__ uint H[NBUCK_MAX];
    const int t = threadIdx.x;
    for (int i = t; i < nbuck; i += 256) H[i] = 0;
    __syncthreads();
    const int r0 = blockIdx.x * chunk;
    const int r1 = min(KP, r0 + chunk);
    for (int r = r0 + t; r < r1; r += 256)
        if (pin[r] >= 0) atomicAdd(&H[((uint)pout[r]) >> BKT_SH], 1u);
    __syncthreads();
    uint* row = cntmat + (size_t)blockIdx.x * nbuck;
    for (int i = t; i < nbuck; i += 256) row[i] = H[i];
}

// p2: per-bucket exclusive scan over CBLK rows. Block = 16 buckets x 16
// segments of (CBLK/16) rows. 16 consecutive buckets = 64B per 16 lanes.
__global__ void p2_colscan(uint* __restrict__ cntmat, uint* __restrict__ btot,
                           int nbuck) {
    const int tid = threadIdx.x;
    const int bi  = tid & 15;
    const int seg = tid >> 4;            // 0..15
    const int b   = blockIdx.x * 16 + bi;
    const int rpseg = CBLK / 16;         // 64 rows per segment
    const bool valid = (b < nbuck);
    uint s = 0;
    if (valid) {
        for (int u = 0; u < rpseg; ++u)
            s += cntmat[(size_t)(seg * rpseg + u) * nbuck + b];
    }
    __shared__ uint ss[16][16];
    ss[seg][bi] = s;
    __syncthreads();
    uint pre = 0;
    for (int g = 0; g < seg; ++g) pre += ss[g][bi];
    if (valid && seg == 15) btot[b] = pre + s;
    if (valid) {
        uint run = pre;
        for (int u = 0; u < rpseg; ++u) {
            size_t idx = (size_t)(seg * rpseg + u) * nbuck + b;
            uint v = cntmat[idx];
            cntmat[idx] = run;           // exclusive over blocks
            run += v;
        }
    }
}

__global__ void p3_bucketscan(const uint* __restrict__ btot, uint* __restrict__ bbase,
                              uint* __restrict__ starts, int nbuck, int N) {
    const int t = threadIdx.x;
    __shared__ uint part[256];
    uint loc[10]; uint s = 0;
#pragma unroll
    for (int u = 0; u < 10; ++u) {
        int i = t * 10 + u;
        loc[u] = (i < nbuck) ? btot[i] : 0;
        s += loc[u];
    }
    part[t] = s;
    __syncthreads();
    for (int off = 1; off < 256; off <<= 1) {
        uint y = (t >= off) ? part[t - off] : 0;
        __syncthreads();
        part[t] += y;
        __syncthreads();
    }
    uint run = part[t] - s;
#pragma unroll
    for (int u = 0; u < 10; ++u) {
        int i = t * 10 + u;
        if (i < nbuck) { bbase[i] = run; run += loc[u]; }
    }
    if (t == 255) { bbase[nbuck] = run; starts[N] = run; }
}

// phase 4: counting-sort block's records by bucket in LDS, write bucket runs.
// bucket id stored in u16 sidecar at placement -> no binary search at write.
__global__ __launch_bounds__(256)
void p4_place(const int* __restrict__ pin, const int* __restrict__ pout,
              const uint* __restrict__ cntmat, const uint* __restrict__ bbase,
              uint* __restrict__ tmp, int KP, int P, int chunk, int nbuck) {
    __shared__ uint recs[LDSCAP];
    __shared__ ushort bof[LDSCAP];
    __shared__ uint H[NBUCK_MAX + 1];
    __shared__ uint C[NBUCK_MAX];
    __shared__ uint part[256];
    const int t = threadIdx.x;
    const int j = blockIdx.x;
    for (int i = t; i < nbuck; i += 256) H[i] = 0;
    __syncthreads();
    const int r0 = j * chunk;
    const int r1 = min(KP, r0 + chunk);
    for (int r = r0 + t; r < r1; r += 256)
        if (pin[r] >= 0) atomicAdd(&H[((uint)pout[r]) >> BKT_SH], 1u);
    __syncthreads();
    uint loc[10]; uint s = 0;
#pragma unroll
    for (int u = 0; u < 10; ++u) {
        int i = t * 10 + u;
        loc[u] = (i < nbuck) ? H[i] : 0;
        s += loc[u];
    }
    __syncthreads();
    part[t] = s;
    __syncthreads();
    for (int off = 1; off < 256; off <<= 1) {
        uint y = (t >= off) ? part[t - off] : 0;
        __syncthreads();
        part[t] += y;
        __syncthreads();
    }
    uint run = part[t] - s;
#pragma unroll
    for (int u = 0; u < 10; ++u) {
        int i = t * 10 + u;
        if (i < nbuck) { uint c = loc[u]; H[i] = run; run += c; }
    }
    if (t == 255) H[nbuck] = run;
    __syncthreads();
    for (int i = t; i < nbuck; i += 256) C[i] = H[i];   // cursors
    __syncthreads();
    for (int r = r0 + t; r < r1; r += 256) {
        int ii = pin[r];
        if (ii < 0) continue;
        uint po = (uint)pout[r];
        uint b = po >> BKT_SH;
        uint k = (uint)r / (uint)P;
        uint pos = atomicAdd(&C[b], 1u);
        recs[pos] = ((po & 127u) << 24) | (k << 19) | (uint)ii;
        bof[pos] = (ushort)b;
    }
    __syncthreads();
    const uint tot = H[nbuck];
    for (int i = t; i < nbuck; i += 256)
        C[i] = bbase[i] + cntmat[(size_t)j * nbuck + i] - H[i];  // dest bias
    __syncthreads();
    for (uint sdx = t; sdx < tot; sdx += 256) {
        uint b = (uint)bof[sdx];
        tmp[C[b] + sdx] = recs[sdx];
    }
}

// phase 5: per-bucket counting-sort by output -> starts + entries.
// entries MAY ALIAS tmp (whole range staged into LDS before any write).
__global__ void p5_fine(const uint* tmp, const uint* __restrict__ bbase,
                        uint* entries, uint* __restrict__ starts, int N) {
    __shared__ uint recs[P3CAP];
    __shared__ uint cnt[128];
    __shared__ uint curl[128];
    const int b = blockIdx.x;
    const int t = threadIdx.x;
    const uint e0 = bbase[b];
    uint nrec = bbase[b + 1] - e0;
    if (nrec > P3CAP) nrec = P3CAP;
    for (uint s = t; s < nrec; s += 256) recs[s] = tmp[e0 + s];
    if (t < 128) { cnt[t] = 0; curl[t] = 0; }
    __syncthreads();
    for (uint s = t; s < nrec; s += 256) atomicAdd(&cnt[recs[s] >> 24], 1u);
    __syncthreads();
    uint orig = (t < 128) ? cnt[t] : 0;
    for (int off = 1; off < 128; off <<= 1) {
        uint y = (t < 128 && t >= off) ? cnt[t - off] : 0;
        __syncthreads();
        if (t < 128) cnt[t] += y;
        __syncthreads();
    }
    if (t < 128) cnt[t] -= orig;
    __syncthreads();
    const int o0 = b << BKT_SH;
    if (t < 128 && o0 + t < N) starts[o0 + t] = e0 + cnt[t];
    for (uint s = t; s < nrec; s += 256) {
        uint lo = recs[s] >> 24;
        uint idx = atomicAdd(&curl[lo], 1u);
        entries[e0 + cnt[lo] + idx] = recs[s] & 0x00FFFFFFu;
    }
}

// ------- CSR-gather MFMA conv: wave-independent (NO block barriers) -------
// (byte-identical logic to round-12 passing version)
template <bool FINAL>
__global__ void conv_csr(const ushort* __restrict__ xb,   // [N+1][32], row N = 0
                         const ushort* __restrict__ Wt,   // [27][32 cout][32 cin]
                         const uint* __restrict__ starts,
                         const uint* __restrict__ entries,
                         const float* __restrict__ iden,
                         float* __restrict__ outf,
                         ushort* __restrict__ outb,
                         int N) {
    const int w  = threadIdx.x >> 6;
    const int l  = threadIdx.x & 63;
    const int m  = l & 15;     // output-within-tile / C col (cout)
    const int iq = l >> 4;     // cin chunk iq*8..+7 ; C rows iq*4..+3
    const int o0 = (blockIdx.x * 4 + w) * 16;

    __shared__ uint eld[4][384];

    if (o0 >= N) return;       // wave-uniform exit; no barriers in this kernel

    const uint s0 = starts[o0];
    const uint sm = starts[o0 + m];
    const uint se = starts[o0 + m + 1];
    uint total = starts[o0 + 16] - s0;
    if (total > 384) total = 384;
    for (uint t = l; t < total; t += 64)
        eld[w][t] = entries[s0 + t];
    asm volatile("s_waitcnt lgkmcnt(0) vmcnt(0)" ::: "memory");
    __builtin_amdgcn_sched_barrier(0);

    if (iq == 0) {
        const uint a = sm - s0, bnd = se - s0;
        for (uint i = a + 1; i < bnd; ++i) {
            uint key = eld[w][i];
            uint j = i;
            while (j > a && eld[w][j - 1] > key) { eld[w][j] = eld[w][j - 1]; --j; }
            eld[w][j] = key;
        }
    }
    asm volatile("s_waitcnt lgkmcnt(0)" ::: "memory");
    __builtin_amdgcn_sched_barrier(0);

    f32x4 c0 = {0.f, 0.f, 0.f, 0.f};
    f32x4 c1 = {0.f, 0.f, 0.f, 0.f};

    uint q = sm - s0;
    const uint e = se - s0;
    uint ent = (q < e) ? eld[w][q] : 0xFFFFFFFFu;

    for (int k = 0; k < 27; ++k) {
        const ushort* wk = Wt + (k << 10);
        U4S8 b0, b1;
        b0.u = *(const uint4*)(wk + m * 32 + iq * 8);
        b1.u = *(const uint4*)(wk + (m + 16) * 32 + iq * 8);

        float a0=0.f,a1=0.f,a2=0.f,a3=0.f,a4=0.f,a5=0.f,a6=0.f,a7=0.f;
        bool got = false;
        while ((ent >> 19) == (uint)k) {
            got = true;
            const uint pi = ent & 0x7FFFFu;
            uint4 v = *(const uint4*)(xb + (size_t)pi * 32 + iq * 8);
            a0 += __uint_as_float(v.x << 16);
            a1 += __uint_as_float(v.x & 0xFFFF0000u);
            a2 += __uint_as_float(v.y << 16);
            a3 += __uint_as_float(v.y & 0xFFFF0000u);
            a4 += __uint_as_float(v.z << 16);
            a5 += __uint_as_float(v.z & 0xFFFF0000u);
            a6 += __uint_as_float(v.w << 16);
            a7 += __uint_as_float(v.w & 0xFFFF0000u);
            ++q;
            ent = (q < e) ? eld[w][q] : 0xFFFFFFFFu;
        }
        if (__any(got)) {
            U4S8 af;
            asm volatile("v_cvt_pk_bf16_f32 %0, %1, %2" : "=v"(af.u.x) : "v"(a0), "v"(a1));
            asm volatile("v_cvt_pk_bf16_f32 %0, %1, %2" : "=v"(af.u.y) : "v"(a2), "v"(a3));
            asm volatile("v_cvt_pk_bf16_f32 %0, %1, %2" : "=v"(af.u.z) : "v"(a4), "v"(a5));
            asm volatile("v_cvt_pk_bf16_f32 %0, %1, %2" : "=v"(af.u.w) : "v"(a6), "v"(a7));
            c0 = __builtin_amdgcn_mfma_f32_16x16x32_bf16(af.s, b0.s, c0, 0, 0, 0);
            c1 = __builtin_amdgcn_mfma_f32_16x16x32_bf16(af.s, b1.s, c1, 0, 0, 0);
        }
    }

#pragma unroll
    for (int j = 0; j < 4; ++j) {
        const long ro = (long)(o0 + iq * 4 + j) * 32;
        if (FINAL) {
            outf[ro + m]      = c0[j] + iden[ro + m];
            outf[ro + 16 + m] = c1[j] + iden[ro + 16 + m];
        } else {
            outb[ro + m]      = f2bf(c0[j]);
            outb[ro + 16 + m] = f2bf(c1[j]);
        }
    }
}

// ---------------- downsample: CSR gather (atomic-free) ----------------
__global__ void ds_gather(const float* __restrict__ xyz,
                          const int* __restrict__ batch,
                          const uint* __restrict__ starts2,
                          const uint* __restrict__ entries2,
                          float* __restrict__ out_xyz,
                          float* __restrict__ out_batch, int M) {
    int o = blockIdx.x * 256 + threadIdx.x;
    if (o >= M) return;
    const uint s = starts2[o], e = starts2[o + 1];
    float sx = 0.f, sy = 0.f, sz = 0.f, sb = 0.f;
    for (uint q = s; q < e; ++q) {
        uint i = entries2[q] & 0x00FFFFFFu;
        sx += xyz[(size_t)i * 3 + 0];
        sy += xyz[(size_t)i * 3 + 1];
        sz += xyz[(size_t)i * 3 + 2];
        sb += (float)batch[i];
    }
    float c = fmaxf((float)(e - s), 1.0f);
    float inv = 1.0f / c;
    out_xyz[(long)o * 3 + 0] = sx * inv;
    out_xyz[(long)o * 3 + 1] = sy * inv;
    out_xyz[(long)o * 3 + 2] = sz * inv;
    out_batch[o] = sb * inv;
}

extern "C" void kernel_launch(void* const* d_in, const int* in_sizes, int n_in,
                              void* d_out, int out_size, void* d_ws, size_t ws_size,
                              hipStream_t stream) {
    const float* feats = (const float*)d_in[0];
    const float* xyz   = (const float*)d_in[1];
    const int*   batch = (const int*)d_in[2];
    const int*   pin   = (const int*)d_in[3];
    const int*   pout  = (const int*)d_in[4];
    const int*   dsin  = (const int*)d_in[5];
    const int*   dsout = (const int*)d_in[6];
    const float* W1    = (const float*)d_in[7];
    const float* W2    = (const float*)d_in[8];

    const int N   = in_sizes[0] / 32;
    const int K   = 27;
    const int P   = in_sizes[3] / K;
    const int KP  = K * P;
    const int P2n = in_sizes[5];
    const int M   = (out_size - N * 32) / 4;
    const int nbuck = (N + 127) >> BKT_SH;       // 2344 for N=300000
    const int chunk = (KP + CBLK - 1) / CBLK;    // 3956 <= LDSCAP
    const int nbuck2 = (M + 127) >> BKT_SH;      // 293
    const int chunk2 = (P2n + CBLK - 1) / CBLK;  // 293

    auto align256 = [](size_t x) { return (x + 255) & ~(size_t)255; };
    char* base = (char*)d_ws;
    size_t off = 0;
    float* stats1 = (float*)(base + off); off += 256;
    float* stats2 = (float*)(base + off); off += 256;
    const size_t zero_end = off;
    uint* cntmat  = (uint*)(base + off);  off = align256(off + (size_t)CBLK * nbuck * 4);
    uint* btot    = (uint*)(base + off);  off = align256(off + (size_t)nbuck * 4);
    uint* bbase   = (uint*)(base + off);  off = align256(off + (size_t)(nbuck + 1) * 4);
    uint* starts  = (uint*)(base + off);  off = align256(off + (size_t)(N + 1) * 4);
    uint* tmp     = (uint*)(base + off);  off = align256(off + (size_t)KP * 4);
    uint* entries = tmp;                  // built in place by p5
    uint* cntmat2 = (uint*)(base + off);  off = align256(off + (size_t)CBLK * nbuck2 * 4);
    uint* btot2   = (uint*)(base + off);  off = align256(off + (size_t)nbuck2 * 4);
    uint* bbase2  = (uint*)(base + off);  off = align256(off + (size_t)(nbuck2 + 1) * 4);
    uint* starts2 = (uint*)(base + off);  off = align256(off + (size_t)(M + 1) * 4);
    uint* tmp2    = (uint*)(base + off);  off = align256(off + (size_t)P2n * 4);
    uint* entries2 = tmp2;                // built in place by p5
    ushort* Wt1   = (ushort*)(base + off); off = align256(off + 27 * 1024 * 2);
    ushort* Wt2   = (ushort*)(base + off); off = align256(off + 27 * 1024 * 2);
    ushort* xb    = (ushort*)(base + off); off = align256(off + (size_t)(N + 1) * 64);
    ushort* hacc  = (ushort*)(base + off); off = align256(off + (size_t)N * 64);

    hipMemsetAsync(d_ws, 0, zero_end, stream);

    // W -> bf16 transposed + zero row N of xb (merged)
    prep<<<(2 * 27 * 1024 + 32 + 255) / 256, 256, 0, stream>>>(W1, W2, Wt1, Wt2, xb, N);

    // CSR build for conv pairs (shared by both convs)
    p1_count<<<CBLK, 256, 0, stream>>>(pin, pout, cntmat, KP, chunk, nbuck);
    p2_colscan<<<(nbuck + 15) / 16, 256, 0, stream>>>(cntmat, btot, nbuck);
    p3_bucketscan<<<1, 256, 0, stream>>>(btot, bbase, starts, nbuck, N);
    p4_place<<<CBLK, 256, 0, stream>>>(pin, pout, cntmat, bbase, tmp, KP, P, chunk, nbuck);
    p5_fine<<<nbuck, 256, 0, stream>>>(tmp, bbase, entries, starts, N);

    // CSR build for downsample pairs (K=1 -> k=0)
    p1_count<<<CBLK, 256, 0, stream>>>(dsin, dsout, cntmat2, P2n, chunk2, nbuck2);
    p2_colscan<<<(nbuck2 + 15) / 16, 256, 0, stream>>>(cntmat2, btot2, nbuck2);
    p3_bucketscan<<<1, 256, 0, stream>>>(btot2, bbase2, starts2, nbuck2, M);
    p4_place<<<CBLK, 256, 0, stream>>>(dsin, dsout, cntmat2, bbase2, tmp2, P2n, P2n, chunk2, nbuck2);
    p5_fine<<<nbuck2, 256, 0, stream>>>(tmp2, bbase2, entries2, starts2, M);

    // conv1: bn_relu(feats) -> W1 -> hacc (bf16)
    stats_f32<<<1024, 256, 0, stream>>>(feats, stats1, N * 8);
    bnrelu_f32<<<(N * 4 + 255) / 256, 256, 0, stream>>>(feats, stats1, xb, N * 4, N);
    const int cblocks = (N / 16 + 3) / 4;
    conv_csr<false><<<cblocks, 256, 0, stream>>>(xb, Wt1, starts, entries,
                                                 nullptr, nullptr, hacc, N);

    // conv2: bn_relu(hacc) -> W2 -> out (+ identity feats)
    stats_bf16<<<1024, 256, 0, stream>>>(hacc, stats2, N * 4);
    bnrelu_bf16<<<(N * 4 + 255) / 256, 256, 0, stream>>>(hacc, stats2, xb, N * 4, N);
    float* out = (float*)d_out;
    conv_csr<true><<<cblocks, 256, 0, stream>>>(xb, Wt2, starts, entries,
                                                feats, out, nullptr, N);

    // downsample: atomic-free CSR gather
    ds_gather<<<(M + 255) / 256, 256, 0, stream>>>(xyz, batch, starts2, entries2,
                                                   out + (size_t)N * 32,
                                                   out + (size_t)N * 32 + (size_t)3 * M,
                                                   M);
}